// Round 1
// baseline (636.365 us; speedup 1.0000x reference)
//
#include <hip/hip_runtime.h>

typedef __bf16 bf16_t;
typedef __bf16 bf16x8 __attribute__((ext_vector_type(8)));
typedef __bf16 bf16x4 __attribute__((ext_vector_type(4)));
typedef float  floatx4 __attribute__((ext_vector_type(4)));

#define D_MODEL 1024
#define S_LEN   2048
#define NHEAD   16
#define DK      64
#define BATCH   4
#define MROWS   (BATCH * S_LEN)   // 8192

// ---------------------------------------------------------------------------
// Weight transpose + fp32->bf16: Wt[n][k] = W[k][n], both 1024x1024.
// ---------------------------------------------------------------------------
__global__ __launch_bounds__(256)
void transpose_w_kernel(const float* __restrict__ W, bf16_t* __restrict__ Wt)
{
  __shared__ float tile[64][65];          // pad 65: transposed reads ~2-way
  const int x0 = blockIdx.x * 64;         // n
  const int y0 = blockIdx.y * 64;         // k
  const int tid = threadIdx.x;
  const int r = tid >> 4;                 // 0..15
  const int c = (tid & 15) << 2;          // 0..60
#pragma unroll
  for (int p = 0; p < 4; p++) {
    floatx4 v = *(const floatx4*)&W[(size_t)(y0 + p * 16 + r) * D_MODEL + x0 + c];
    tile[p * 16 + r][c + 0] = v[0];
    tile[p * 16 + r][c + 1] = v[1];
    tile[p * 16 + r][c + 2] = v[2];
    tile[p * 16 + r][c + 3] = v[3];
  }
  __syncthreads();
#pragma unroll
  for (int p = 0; p < 4; p++) {
    int row = p * 16 + r;                 // n offset within tile
    bf16x4 o;
    o[0] = (bf16_t)tile[c + 0][row];
    o[1] = (bf16_t)tile[c + 1][row];
    o[2] = (bf16_t)tile[c + 2][row];
    o[3] = (bf16_t)tile[c + 3][row];
    *(bf16x4*)&Wt[(size_t)(x0 + row) * D_MODEL + y0 + c] = o;
  }
}

// ---------------------------------------------------------------------------
// GEMM: C = A @ W + bias.  A: [8192,1024] (AMODE 0: fp32, 1: bf16).
// Wt: [N][K] bf16 (pre-transposed).  Tile 128x128, BK=32, 4 waves (2x2).
// OMODE 0: bf16 out [B,H,S,DK] (q/k) | 1: bf16 out [B,H,DK,S] (v^T) |
// OMODE 2: fp32 out [M,N] (final).
// MFMA 16x16x32 bf16; C/D layout col=lane&15, row=quad*4+reg (m89-verified).
// ---------------------------------------------------------------------------
template<int AMODE, int OMODE>
__global__ __launch_bounds__(256)
void gemm_kernel(const void* __restrict__ Av, const bf16_t* __restrict__ Wt,
                 const float* __restrict__ bias, void* __restrict__ outv)
{
  __shared__ bf16_t As[128][40];   // [m][k], pad 40 (80B=20 banks -> 2-way)
  __shared__ bf16_t Bs[128][40];   // [n][k]
  const int m0 = blockIdx.y << 7;
  const int n0 = blockIdx.x << 7;
  const int tid = threadIdx.x;
  const int lane = tid & 63;
  const int w = tid >> 6;
  const int l15 = lane & 15;
  const int quad = lane >> 4;
  const int wy = (w >> 1) << 6;    // 0 / 64
  const int wx = (w & 1) << 6;

  floatx4 acc[4][4];
#pragma unroll
  for (int i = 0; i < 4; i++)
#pragma unroll
    for (int j = 0; j < 4; j++)
#pragma unroll
      for (int r = 0; r < 4; r++) acc[i][j][r] = 0.0f;

  for (int kt = 0; kt < 32; kt++) {
    const int k0 = kt << 5;
    __syncthreads();
    if constexpr (AMODE == 0) {
      const float* A = (const float*)Av;
#pragma unroll
      for (int p = 0; p < 4; p++) {
        int idx = p * 256 + tid;
        int r = idx >> 3, c = idx & 7;
        floatx4 v = *(const floatx4*)&A[(size_t)(m0 + r) * D_MODEL + k0 + (c << 2)];
        bf16x4 o;
        o[0] = (bf16_t)v[0]; o[1] = (bf16_t)v[1];
        o[2] = (bf16_t)v[2]; o[3] = (bf16_t)v[3];
        *(bf16x4*)&As[r][c << 2] = o;
      }
    } else {
      const bf16_t* A = (const bf16_t*)Av;
#pragma unroll
      for (int p = 0; p < 2; p++) {
        int idx = p * 256 + tid;
        int r = idx >> 2, c = idx & 3;
        *(bf16x8*)&As[r][c << 3] =
            *(const bf16x8*)&A[(size_t)(m0 + r) * D_MODEL + k0 + (c << 3)];
      }
    }
#pragma unroll
    for (int p = 0; p < 2; p++) {
      int idx = p * 256 + tid;
      int r = idx >> 2, c = idx & 3;
      *(bf16x8*)&Bs[r][c << 3] =
          *(const bf16x8*)&Wt[(size_t)(n0 + r) * D_MODEL + k0 + (c << 3)];
    }
    __syncthreads();

    bf16x8 af[4], bfv[4];
#pragma unroll
    for (int mi = 0; mi < 4; mi++)
      af[mi] = *(const bf16x8*)&As[wy + mi * 16 + l15][quad << 3];
#pragma unroll
    for (int ni = 0; ni < 4; ni++)
      bfv[ni] = *(const bf16x8*)&Bs[wx + ni * 16 + l15][quad << 3];
#pragma unroll
    for (int mi = 0; mi < 4; mi++)
#pragma unroll
      for (int ni = 0; ni < 4; ni++)
        acc[mi][ni] = __builtin_amdgcn_mfma_f32_16x16x32_bf16(
            af[mi], bfv[ni], acc[mi][ni], 0, 0, 0);
  }

#pragma unroll
  for (int mi = 0; mi < 4; mi++) {
#pragma unroll
    for (int ni = 0; ni < 4; ni++) {
      const int nbase = n0 + wx + ni * 16 + l15;
      const float bv = bias[nbase];
#pragma unroll
      for (int r = 0; r < 4; r++) {
        const int m = m0 + wy + mi * 16 + quad * 4 + r;
        float v = acc[mi][ni][r] + bv;
        if constexpr (OMODE == 0) {
          int b = m >> 11, s = m & (S_LEN - 1);
          int h = nbase >> 6, d = nbase & 63;
          ((bf16_t*)outv)[((((size_t)(b * NHEAD + h) << 11) + s) << 6) + d] = (bf16_t)v;
        } else if constexpr (OMODE == 1) {
          int b = m >> 11, s = m & (S_LEN - 1);
          int h = nbase >> 6, d = nbase & 63;
          ((bf16_t*)outv)[((((size_t)(b * NHEAD + h) << 6) + d) << 11) + s] = (bf16_t)v;
        } else {
          ((float*)outv)[((size_t)m << 10) + nbase] = v;
        }
      }
    }
  }
}

// ---------------------------------------------------------------------------
// Causal flash attention. Block = (q-tile of 128 rows, one (b,h)).
// 4 waves x 32 q-rows. K-tiles of 64 keys staged in LDS; Vt is [d][s] so the
// PV B-fragment is a contiguous ds_read_b128. P does the C-layout -> A-layout
// transform through wave-private LDS (m120 pattern).
// ---------------------------------------------------------------------------
__global__ __launch_bounds__(256)
void attn_kernel(const bf16_t* __restrict__ qp, const bf16_t* __restrict__ kp,
                 const bf16_t* __restrict__ vtp, bf16_t* __restrict__ ob)
{
  __shared__ bf16_t Kt[64][72];      // [key][d]   pad 72 -> 2-way
  __shared__ bf16_t Vts[64][72];     // [d][key]
  __shared__ bf16_t Ps[4][32][72];   // per-wave P [qrow][key]

  const int qt = blockIdx.x;         // 0..15
  const int bh = blockIdx.y;         // 0..63
  const int q0 = qt << 7;
  const int tid = threadIdx.x;
  const int w = tid >> 6;
  const int lane = tid & 63;
  const int l15 = lane & 15;
  const int quad = lane >> 4;
  const int qbase = q0 + w * 32;

  const bf16_t* Qh = qp + ((size_t)bh * S_LEN * DK);
  const bf16_t* Kh = kp + ((size_t)bh * S_LEN * DK);
  const bf16_t* Vh = vtp + ((size_t)bh * S_LEN * DK);  // [64][2048]

  // Q fragments held in registers for the whole K loop.
  bf16x8 qf[2][2];
#pragma unroll
  for (int mi = 0; mi < 2; mi++)
#pragma unroll
    for (int ks = 0; ks < 2; ks++)
      qf[mi][ks] = *(const bf16x8*)&Qh[(size_t)(qbase + mi * 16 + l15) * DK +
                                       ks * 32 + (quad << 3)];

  floatx4 acc_o[2][4];
  float m_i[2][4], l_i[2][4];
#pragma unroll
  for (int mi = 0; mi < 2; mi++)
#pragma unroll
    for (int r = 0; r < 4; r++) { m_i[mi][r] = -1e30f; l_i[mi][r] = 0.0f; }
#pragma unroll
  for (int mi = 0; mi < 2; mi++)
#pragma unroll
    for (int nd = 0; nd < 4; nd++)
#pragma unroll
      for (int r = 0; r < 4; r++) acc_o[mi][nd][r] = 0.0f;

  const int nkt = (qt << 1) + 2;     // causal: keys <= q0+127 only
  for (int kt = 0; kt < nkt; kt++) {
    const int k0 = kt << 6;
    __syncthreads();
#pragma unroll
    for (int p = 0; p < 2; p++) {
      int idx = p * 256 + tid;
      int r = idx >> 3, c = (idx & 7) << 3;
      *(bf16x8*)&Kt[r][c]  = *(const bf16x8*)&Kh[(size_t)(k0 + r) * DK + c];
      *(bf16x8*)&Vts[r][c] = *(const bf16x8*)&Vh[(size_t)r * S_LEN + k0 + c];
    }
    __syncthreads();

    // S = Q K^T  (32 q-rows x 64 keys per wave)
    floatx4 acc_s[2][4];
#pragma unroll
    for (int mi = 0; mi < 2; mi++)
#pragma unroll
      for (int ni = 0; ni < 4; ni++)
#pragma unroll
        for (int r = 0; r < 4; r++) acc_s[mi][ni][r] = 0.0f;
#pragma unroll
    for (int ks = 0; ks < 2; ks++) {
      bf16x8 bk[4];
#pragma unroll
      for (int ni = 0; ni < 4; ni++)
        bk[ni] = *(const bf16x8*)&Kt[ni * 16 + l15][ks * 32 + (quad << 3)];
#pragma unroll
      for (int mi = 0; mi < 2; mi++)
#pragma unroll
        for (int ni = 0; ni < 4; ni++)
          acc_s[mi][ni] = __builtin_amdgcn_mfma_f32_16x16x32_bf16(
              qf[mi][ks], bk[ni], acc_s[mi][ni], 0, 0, 0);
    }

    // scale + causal mask + row max
    float rowmax[2][4], rowsum[2][4], alpha[2][4];
#pragma unroll
    for (int mi = 0; mi < 2; mi++)
#pragma unroll
      for (int r = 0; r < 4; r++) rowmax[mi][r] = -1e30f;
#pragma unroll
    for (int mi = 0; mi < 2; mi++) {
#pragma unroll
      for (int ni = 0; ni < 4; ni++) {
        const int key = k0 + ni * 16 + l15;
#pragma unroll
        for (int r = 0; r < 4; r++) {
          const int qrow = qbase + mi * 16 + quad * 4 + r;
          float sv = acc_s[mi][ni][r] * 0.125f;         // 1/sqrt(64)
          sv = (key > qrow) ? -1e30f : sv;
          acc_s[mi][ni][r] = sv;
          rowmax[mi][r] = fmaxf(rowmax[mi][r], sv);
        }
      }
    }
#pragma unroll
    for (int mi = 0; mi < 2; mi++)
#pragma unroll
      for (int r = 0; r < 4; r++) {
        float v = rowmax[mi][r];
        v = fmaxf(v, __shfl_xor(v, 1));
        v = fmaxf(v, __shfl_xor(v, 2));
        v = fmaxf(v, __shfl_xor(v, 4));
        v = fmaxf(v, __shfl_xor(v, 8));
        rowmax[mi][r] = v;
      }
#pragma unroll
    for (int mi = 0; mi < 2; mi++)
#pragma unroll
      for (int r = 0; r < 4; r++) {
        float mn = fmaxf(m_i[mi][r], rowmax[mi][r]);
        alpha[mi][r] = __expf(m_i[mi][r] - mn);
        m_i[mi][r] = mn;
        rowsum[mi][r] = 0.0f;
      }
    // P = exp(S - m); accumulate row sums; stash P to LDS (bf16)
#pragma unroll
    for (int mi = 0; mi < 2; mi++) {
#pragma unroll
      for (int ni = 0; ni < 4; ni++) {
#pragma unroll
        for (int r = 0; r < 4; r++) {
          float p = __expf(acc_s[mi][ni][r] - m_i[mi][r]);
          rowsum[mi][r] += p;
          Ps[w][mi * 16 + quad * 4 + r][ni * 16 + l15] = (bf16_t)p;
        }
      }
    }
#pragma unroll
    for (int mi = 0; mi < 2; mi++)
#pragma unroll
      for (int r = 0; r < 4; r++) {
        float v = rowsum[mi][r];
        v += __shfl_xor(v, 1);
        v += __shfl_xor(v, 2);
        v += __shfl_xor(v, 4);
        v += __shfl_xor(v, 8);
        l_i[mi][r] = l_i[mi][r] * alpha[mi][r] + v;
      }
    // rescale O
#pragma unroll
    for (int mi = 0; mi < 2; mi++)
#pragma unroll
      for (int nd = 0; nd < 4; nd++)
#pragma unroll
        for (int r = 0; r < 4; r++) acc_o[mi][nd][r] *= alpha[mi][r];

    // O += P @ V  (A = Ps in A-layout, B = Vts[d][key])
#pragma unroll
    for (int ks = 0; ks < 2; ks++) {
      bf16x8 av[2], bv[4];
#pragma unroll
      for (int mi = 0; mi < 2; mi++)
        av[mi] = *(const bf16x8*)&Ps[w][mi * 16 + l15][ks * 32 + (quad << 3)];
#pragma unroll
      for (int nd = 0; nd < 4; nd++)
        bv[nd] = *(const bf16x8*)&Vts[nd * 16 + l15][ks * 32 + (quad << 3)];
#pragma unroll
      for (int mi = 0; mi < 2; mi++)
#pragma unroll
        for (int nd = 0; nd < 4; nd++)
          acc_o[mi][nd] = __builtin_amdgcn_mfma_f32_16x16x32_bf16(
              av[mi], bv[nd], acc_o[mi][nd], 0, 0, 0);
    }
  }

  // epilogue: O /= l, write [B, S, H*64] bf16
  const int b = bh >> 4, h = bh & 15;
#pragma unroll
  for (int mi = 0; mi < 2; mi++) {
#pragma unroll
    for (int r = 0; r < 4; r++) {
      const float inv = 1.0f / l_i[mi][r];
      const int s = qbase + mi * 16 + quad * 4 + r;
#pragma unroll
      for (int nd = 0; nd < 4; nd++) {
        const int d = nd * 16 + l15;
        ob[(((size_t)(b * S_LEN + s)) << 10) + h * 64 + d] =
            (bf16_t)(acc_o[mi][nd][r] * inv);
      }
    }
  }
}

// ---------------------------------------------------------------------------
extern "C" void kernel_launch(void* const* d_in, const int* in_sizes, int n_in,
                              void* d_out, int out_size, void* d_ws, size_t ws_size,
                              hipStream_t stream)
{
  (void)in_sizes; (void)n_in; (void)out_size; (void)ws_size;
  const float* Q  = (const float*)d_in[0];
  const float* K  = (const float*)d_in[1];
  const float* V  = (const float*)d_in[2];
  // d_in[3] = mask (causal, implemented analytically)
  const float* Wq = (const float*)d_in[4];
  const float* bq = (const float*)d_in[5];
  const float* Wk = (const float*)d_in[6];
  const float* bk = (const float*)d_in[7];
  const float* Wv = (const float*)d_in[8];
  const float* bv = (const float*)d_in[9];
  const float* Wo = (const float*)d_in[10];
  const float* bo = (const float*)d_in[11];
  float* out = (float*)d_out;

  const size_t NELT = (size_t)MROWS * D_MODEL;      // 8M
  bf16_t* qp  = (bf16_t*)d_ws;                      // [B,H,S,DK]
  bf16_t* kp  = qp + NELT;                          // [B,H,S,DK]
  bf16_t* vtp = kp + NELT;                          // [B,H,DK,S]
  bf16_t* obuf = vtp + NELT;                        // [B,S,H*DK]
  bf16_t* wqt = obuf + NELT;                        // 4x [N][K] bf16
  bf16_t* wkt = wqt + (size_t)D_MODEL * D_MODEL;
  bf16_t* wvt = wkt + (size_t)D_MODEL * D_MODEL;
  bf16_t* wot = wvt + (size_t)D_MODEL * D_MODEL;

  dim3 blk(256);
  dim3 gT(16, 16);
  transpose_w_kernel<<<gT, blk, 0, stream>>>(Wq, wqt);
  transpose_w_kernel<<<gT, blk, 0, stream>>>(Wk, wkt);
  transpose_w_kernel<<<gT, blk, 0, stream>>>(Wv, wvt);
  transpose_w_kernel<<<gT, blk, 0, stream>>>(Wo, wot);

  dim3 gG(D_MODEL / 128, MROWS / 128);              // (8, 64)
  gemm_kernel<0, 0><<<gG, blk, 0, stream>>>(Q, wqt, bq, qp);
  gemm_kernel<0, 0><<<gG, blk, 0, stream>>>(K, wkt, bk, kp);
  gemm_kernel<0, 1><<<gG, blk, 0, stream>>>(V, wvt, bv, vtp);

  attn_kernel<<<dim3(S_LEN / 128, BATCH * NHEAD), blk, 0, stream>>>(qp, kp, vtp, obuf);

  gemm_kernel<1, 2><<<gG, blk, 0, stream>>>(obuf, wot, bo, out);
}

// Round 2
// 533.179 us; speedup vs baseline: 1.1935x; 1.1935x over previous
//
#include <hip/hip_runtime.h>

typedef __bf16 bf16_t;
typedef __bf16 bf16x8 __attribute__((ext_vector_type(8)));
typedef __bf16 bf16x4 __attribute__((ext_vector_type(4)));
typedef float  floatx4 __attribute__((ext_vector_type(4)));

#define D_MODEL 1024
#define S_LEN   2048
#define NHEAD   16
#define DK      64
#define BATCH   4
#define MROWS   (BATCH * S_LEN)   // 8192
// 1/sqrt(64) * log2(e): fold into Q so scores arrive in exp2 domain
#define QSCALE  0.18033688011112042f

__device__ __forceinline__ void load_lds16(const void* gsrc, void* ldst) {
  __builtin_amdgcn_global_load_lds(
      (const __attribute__((address_space(1))) void*)gsrc,
      (__attribute__((address_space(3))) void*)ldst, 16, 0, 0);
}

// ---------------------------------------------------------------------------
// Fused weight transpose + fp32->bf16 for all 4 weights (z selects).
// ---------------------------------------------------------------------------
__global__ __launch_bounds__(256)
void transpose_w_kernel(const float* __restrict__ W0, const float* __restrict__ W1,
                        const float* __restrict__ W2, const float* __restrict__ W3,
                        bf16_t* __restrict__ T0, bf16_t* __restrict__ T1,
                        bf16_t* __restrict__ T2, bf16_t* __restrict__ T3)
{
  const int z = blockIdx.z;
  const float* W = z == 0 ? W0 : (z == 1 ? W1 : (z == 2 ? W2 : W3));
  bf16_t* Wt     = z == 0 ? T0 : (z == 1 ? T1 : (z == 2 ? T2 : T3));

  __shared__ float tile[64][65];
  const int x0 = blockIdx.x * 64;         // n
  const int y0 = blockIdx.y * 64;         // k
  const int tid = threadIdx.x;
  const int r = tid >> 4;
  const int c = (tid & 15) << 2;
#pragma unroll
  for (int p = 0; p < 4; p++) {
    floatx4 v = *(const floatx4*)&W[(size_t)(y0 + p * 16 + r) * D_MODEL + x0 + c];
    tile[p * 16 + r][c + 0] = v[0];
    tile[p * 16 + r][c + 1] = v[1];
    tile[p * 16 + r][c + 2] = v[2];
    tile[p * 16 + r][c + 3] = v[3];
  }
  __syncthreads();
#pragma unroll
  for (int p = 0; p < 4; p++) {
    int row = p * 16 + r;
    bf16x4 o;
    o[0] = (bf16_t)tile[c + 0][row];
    o[1] = (bf16_t)tile[c + 1][row];
    o[2] = (bf16_t)tile[c + 2][row];
    o[3] = (bf16_t)tile[c + 3][row];
    *(bf16x4*)&Wt[(size_t)(x0 + row) * D_MODEL + y0 + c] = o;
  }
}

// ---------------------------------------------------------------------------
// Fused Q/K/V projection GEMM (z = 0/1/2). A fp32 staged+converted via regs;
// W (bf16, pre-transposed [N][K]) staged via global_load_lds w/ XOR swizzle.
// z=0: q out [B,H,S,DK] * QSCALE | z=1: k out [B,H,S,DK] | z=2: v^T [B,H,DK,S]
// ---------------------------------------------------------------------------
__global__ __launch_bounds__(256)
void proj_kernel(const float* __restrict__ Qi, const float* __restrict__ Ki,
                 const float* __restrict__ Vi,
                 const bf16_t* __restrict__ wq, const bf16_t* __restrict__ wk,
                 const bf16_t* __restrict__ wv,
                 const float* __restrict__ bqp, const float* __restrict__ bkp,
                 const float* __restrict__ bvp,
                 bf16_t* __restrict__ qo, bf16_t* __restrict__ ko,
                 bf16_t* __restrict__ vo)
{
  const int z = blockIdx.z;
  const float* A    = z == 0 ? Qi : (z == 1 ? Ki : Vi);
  const bf16_t* Wt  = z == 0 ? wq : (z == 1 ? wk : wv);
  const float* bias = z == 0 ? bqp : (z == 1 ? bkp : bvp);

  __shared__ bf16_t As[128 * 40];   // padded LD=40 (reg-staged, fp32 convert)
  __shared__ bf16_t Bs[128 * 32];   // linear, global_load_lds + XOR swizzle

  const int m0 = blockIdx.y << 7;
  const int n0 = blockIdx.x << 7;
  const int tid = threadIdx.x;
  const int lane = tid & 63;
  const int w = tid >> 6;
  const int l15 = lane & 15;
  const int quad = lane >> 4;
  const int wy = (w >> 1) << 6;
  const int wx = (w & 1) << 6;
  const int w64 = w << 6;

  floatx4 acc[4][4];
#pragma unroll
  for (int i = 0; i < 4; i++)
#pragma unroll
    for (int j = 0; j < 4; j++)
#pragma unroll
      for (int r = 0; r < 4; r++) acc[i][j][r] = 0.0f;

  for (int kt = 0; kt < 32; kt++) {
    const int k0 = kt << 5;
    __syncthreads();
    // B via global_load_lds, chunk slot s holds (row=s>>2, kc=(s&3)^(row&3))
#pragma unroll
    for (int p = 0; p < 2; p++) {
      int slot = p * 256 + w64 + lane;
      int row = slot >> 2;
      int kc = (slot & 3) ^ (row & 3);
      load_lds16(&Wt[(size_t)(n0 + row) * D_MODEL + k0 + (kc << 3)],
                 &Bs[(size_t)(p * 256 + w64) << 3]);
    }
    // A fp32 -> bf16 via regs
#pragma unroll
    for (int p = 0; p < 4; p++) {
      int idx = p * 256 + tid;
      int r = idx >> 3, c = idx & 7;
      floatx4 v = *(const floatx4*)&A[(size_t)(m0 + r) * D_MODEL + k0 + (c << 2)];
      bf16x4 o;
      o[0] = (bf16_t)v[0]; o[1] = (bf16_t)v[1];
      o[2] = (bf16_t)v[2]; o[3] = (bf16_t)v[3];
      *(bf16x4*)&As[r * 40 + (c << 2)] = o;
    }
    __syncthreads();

    bf16x8 af[4], bfv[4];
#pragma unroll
    for (int mi = 0; mi < 4; mi++) {
      int m = wy + mi * 16 + l15;
      af[mi] = *(const bf16x8*)&As[m * 40 + (quad << 3)];
    }
#pragma unroll
    for (int ni = 0; ni < 4; ni++) {
      int n = wx + ni * 16 + l15;
      bfv[ni] = *(const bf16x8*)&Bs[n * 32 + ((quad ^ (n & 3)) << 3)];
    }
#pragma unroll
    for (int mi = 0; mi < 4; mi++)
#pragma unroll
      for (int ni = 0; ni < 4; ni++)
        acc[mi][ni] = __builtin_amdgcn_mfma_f32_16x16x32_bf16(
            af[mi], bfv[ni], acc[mi][ni], 0, 0, 0);
  }

  const float scl = (z == 0) ? QSCALE : 1.0f;
  bf16_t* outp = z == 0 ? qo : (z == 1 ? ko : vo);
#pragma unroll
  for (int mi = 0; mi < 4; mi++) {
#pragma unroll
    for (int ni = 0; ni < 4; ni++) {
      const int nbase = n0 + wx + ni * 16 + l15;
      const float bv = bias[nbase];
      const int h = nbase >> 6, d = nbase & 63;
#pragma unroll
      for (int r = 0; r < 4; r++) {
        const int m = m0 + wy + mi * 16 + quad * 4 + r;
        const int b = m >> 11, s = m & (S_LEN - 1);
        float v = (acc[mi][ni][r] + bv) * scl;
        if (z < 2) {
          outp[((((size_t)(b * NHEAD + h) << 11) + s) << 6) + d] = (bf16_t)v;
        } else {
          outp[((((size_t)(b * NHEAD + h) << 6) + d) << 11) + s] = (bf16_t)v;
        }
      }
    }
  }
}

// ---------------------------------------------------------------------------
// Output GEMM: out = obuf(bf16) @ Wo + bo, fp32 out. Both operands via
// global_load_lds with XOR swizzle.
// ---------------------------------------------------------------------------
__global__ __launch_bounds__(256)
void out_gemm_kernel(const bf16_t* __restrict__ A, const bf16_t* __restrict__ Wt,
                     const float* __restrict__ bias, float* __restrict__ out)
{
  __shared__ bf16_t As[128 * 32];
  __shared__ bf16_t Bs[128 * 32];
  const int m0 = blockIdx.y << 7;
  const int n0 = blockIdx.x << 7;
  const int tid = threadIdx.x;
  const int lane = tid & 63;
  const int w = tid >> 6;
  const int l15 = lane & 15;
  const int quad = lane >> 4;
  const int wy = (w >> 1) << 6;
  const int wx = (w & 1) << 6;
  const int w64 = w << 6;

  floatx4 acc[4][4];
#pragma unroll
  for (int i = 0; i < 4; i++)
#pragma unroll
    for (int j = 0; j < 4; j++)
#pragma unroll
      for (int r = 0; r < 4; r++) acc[i][j][r] = 0.0f;

  for (int kt = 0; kt < 32; kt++) {
    const int k0 = kt << 5;
    __syncthreads();
#pragma unroll
    for (int p = 0; p < 2; p++) {
      int slot = p * 256 + w64 + lane;
      int row = slot >> 2;
      int kc = (slot & 3) ^ (row & 3);
      load_lds16(&A[(size_t)(m0 + row) * D_MODEL + k0 + (kc << 3)],
                 &As[(size_t)(p * 256 + w64) << 3]);
      load_lds16(&Wt[(size_t)(n0 + row) * D_MODEL + k0 + (kc << 3)],
                 &Bs[(size_t)(p * 256 + w64) << 3]);
    }
    __syncthreads();

    bf16x8 af[4], bfv[4];
#pragma unroll
    for (int mi = 0; mi < 4; mi++) {
      int m = wy + mi * 16 + l15;
      af[mi] = *(const bf16x8*)&As[m * 32 + ((quad ^ (m & 3)) << 3)];
    }
#pragma unroll
    for (int ni = 0; ni < 4; ni++) {
      int n = wx + ni * 16 + l15;
      bfv[ni] = *(const bf16x8*)&Bs[n * 32 + ((quad ^ (n & 3)) << 3)];
    }
#pragma unroll
    for (int mi = 0; mi < 4; mi++)
#pragma unroll
      for (int ni = 0; ni < 4; ni++)
        acc[mi][ni] = __builtin_amdgcn_mfma_f32_16x16x32_bf16(
            af[mi], bfv[ni], acc[mi][ni], 0, 0, 0);
  }

#pragma unroll
  for (int mi = 0; mi < 4; mi++) {
#pragma unroll
    for (int ni = 0; ni < 4; ni++) {
      const int nbase = n0 + wx + ni * 16 + l15;
      const float bv = bias[nbase];
#pragma unroll
      for (int r = 0; r < 4; r++) {
        const int m = m0 + wy + mi * 16 + quad * 4 + r;
        out[((size_t)m << 10) + nbase] = acc[mi][ni][r] + bv;
      }
    }
  }
}

// ---------------------------------------------------------------------------
// Causal flash attention, barrier-free inner loop.
// Block = 128 q-rows of one (b,h); each wave owns 32 q-rows and free-runs its
// own k-loop, reading K / V^T fragments directly from global (L1/L2-hot).
// Q pre-scaled by QSCALE -> scores already in exp2 domain.
// LDS only for the per-wave P C-layout->A-layout roundtrip (LD=68: 2-way max).
// Row-sums come free from a ones-vector MFMA.
// ---------------------------------------------------------------------------
__global__ __launch_bounds__(256)
void attn_kernel(const bf16_t* __restrict__ qp, const bf16_t* __restrict__ kp,
                 const bf16_t* __restrict__ vtp, bf16_t* __restrict__ ob)
{
  __shared__ bf16_t Ps[4][32][68];

  const int qt = 15 - blockIdx.x;          // big blocks dispatched first
  const int bh = blockIdx.y;
  const int q0 = qt << 7;
  const int tid = threadIdx.x;
  const int w = tid >> 6;
  const int lane = tid & 63;
  const int l15 = lane & 15;
  const int quad = lane >> 4;
  const int qbase = q0 + w * 32;

  const bf16_t* Qh = qp + ((size_t)bh << 17);
  const bf16_t* Kh = kp + ((size_t)bh << 17);
  const bf16_t* Vh = vtp + ((size_t)bh << 17);   // [64][2048]

  bf16x8 qf[2][2];
#pragma unroll
  for (int mi = 0; mi < 2; mi++)
#pragma unroll
    for (int ks = 0; ks < 2; ks++)
      qf[mi][ks] = *(const bf16x8*)&Qh[(size_t)(qbase + mi * 16 + l15) * DK +
                                       ks * 32 + (quad << 3)];

  bf16x8 ones;
#pragma unroll
  for (int i = 0; i < 8; i++) ones[i] = (bf16_t)1.0f;

  floatx4 acc_o[2][4];
  float m_i[2][4], l_i[2][4];
#pragma unroll
  for (int mi = 0; mi < 2; mi++)
#pragma unroll
    for (int r = 0; r < 4; r++) { m_i[mi][r] = -1e30f; l_i[mi][r] = 0.0f; }
#pragma unroll
  for (int mi = 0; mi < 2; mi++)
#pragma unroll
    for (int nd = 0; nd < 4; nd++)
#pragma unroll
      for (int r = 0; r < 4; r++) acc_o[mi][nd][r] = 0.0f;

  const int key0 = l15;                 // + k0 + ni*16
  const int row0 = qbase + quad * 4;    // + mi*16 + r
  const int nkb = (qbase + 95) >> 6;    // covers keys up to qbase+31

  for (int kb = 0; kb < nkb; kb++) {
    const int k0 = kb << 6;

    // ---- S = Q K^T (32 q x 64 k), B-frags straight from global ----
    floatx4 acc_s[2][4];
#pragma unroll
    for (int mi = 0; mi < 2; mi++)
#pragma unroll
      for (int ni = 0; ni < 4; ni++)
#pragma unroll
        for (int r = 0; r < 4; r++) acc_s[mi][ni][r] = 0.0f;
#pragma unroll
    for (int ks = 0; ks < 2; ks++) {
      bf16x8 bk[4];
#pragma unroll
      for (int ni = 0; ni < 4; ni++)
        bk[ni] = *(const bf16x8*)&Kh[(size_t)(k0 + ni * 16 + l15) * DK +
                                     ks * 32 + (quad << 3)];
#pragma unroll
      for (int mi = 0; mi < 2; mi++)
#pragma unroll
        for (int ni = 0; ni < 4; ni++)
          acc_s[mi][ni] = __builtin_amdgcn_mfma_f32_16x16x32_bf16(
              qf[mi][ks], bk[ni], acc_s[mi][ni], 0, 0, 0);
    }

    // ---- causal mask: only the diagonal step needs it ----
    if (kb == nkb - 1) {
#pragma unroll
      for (int mi = 0; mi < 2; mi++)
#pragma unroll
        for (int ni = 0; ni < 4; ni++) {
          const int key = k0 + ni * 16 + key0;
#pragma unroll
          for (int r = 0; r < 4; r++)
            if (key > row0 + mi * 16 + r) acc_s[mi][ni][r] = -1e30f;
        }
    }

    // ---- rowmax (regs + 4 shuffles over l15) ----
    float alpha[2][4];
#pragma unroll
    for (int mi = 0; mi < 2; mi++) {
#pragma unroll
      for (int r = 0; r < 4; r++) {
        float v = fmaxf(fmaxf(acc_s[mi][0][r], acc_s[mi][1][r]),
                        fmaxf(acc_s[mi][2][r], acc_s[mi][3][r]));
        v = fmaxf(v, __shfl_xor(v, 1));
        v = fmaxf(v, __shfl_xor(v, 2));
        v = fmaxf(v, __shfl_xor(v, 4));
        v = fmaxf(v, __shfl_xor(v, 8));
        float mn = fmaxf(m_i[mi][r], v);
        alpha[mi][r] = __builtin_amdgcn_exp2f(m_i[mi][r] - mn);
        m_i[mi][r] = mn;
      }
    }

    // ---- P = exp2(S - m), stash to per-wave LDS (conflict-free LD=68) ----
#pragma unroll
    for (int mi = 0; mi < 2; mi++)
#pragma unroll
      for (int ni = 0; ni < 4; ni++)
#pragma unroll
        for (int r = 0; r < 4; r++) {
          float p = __builtin_amdgcn_exp2f(acc_s[mi][ni][r] - m_i[mi][r]);
          Ps[w][mi * 16 + quad * 4 + r][ni * 16 + l15] = (bf16_t)p;
        }

    // ---- rescale O ----
#pragma unroll
    for (int mi = 0; mi < 2; mi++)
#pragma unroll
      for (int nd = 0; nd < 4; nd++)
#pragma unroll
        for (int r = 0; r < 4; r++) acc_o[mi][nd][r] *= alpha[mi][r];

    // ---- read P back in A-layout; rowsum via ones-MFMA; O += P V ----
    bf16x8 av[2][2];
#pragma unroll
    for (int mi = 0; mi < 2; mi++)
#pragma unroll
      for (int ks = 0; ks < 2; ks++)
        av[mi][ks] = *(const bf16x8*)&Ps[w][mi * 16 + l15][ks * 32 + (quad << 3)];

    floatx4 acc_l[2];
#pragma unroll
    for (int mi = 0; mi < 2; mi++) {
#pragma unroll
      for (int r = 0; r < 4; r++) acc_l[mi][r] = 0.0f;
#pragma unroll
      for (int ks = 0; ks < 2; ks++)
        acc_l[mi] = __builtin_amdgcn_mfma_f32_16x16x32_bf16(
            av[mi][ks], ones, acc_l[mi], 0, 0, 0);
    }

#pragma unroll
    for (int ks = 0; ks < 2; ks++) {
      bf16x8 bv[4];
#pragma unroll
      for (int nd = 0; nd < 4; nd++)
        bv[nd] = *(const bf16x8*)&Vh[(size_t)(nd * 16 + l15) * S_LEN +
                                     k0 + ks * 32 + (quad << 3)];
#pragma unroll
      for (int mi = 0; mi < 2; mi++)
#pragma unroll
        for (int nd = 0; nd < 4; nd++)
          acc_o[mi][nd] = __builtin_amdgcn_mfma_f32_16x16x32_bf16(
              av[mi][ks], bv[nd], acc_o[mi][nd], 0, 0, 0);
    }

#pragma unroll
    for (int mi = 0; mi < 2; mi++)
#pragma unroll
      for (int r = 0; r < 4; r++)
        l_i[mi][r] = l_i[mi][r] * alpha[mi][r] + acc_l[mi][r];
  }

  // ---- epilogue: O /= l, write [B, S, H*64] bf16 ----
  const int b = bh >> 4, h = bh & 15;
#pragma unroll
  for (int mi = 0; mi < 2; mi++) {
#pragma unroll
    for (int r = 0; r < 4; r++) {
      const float inv = 1.0f / l_i[mi][r];
      const int s = qbase + mi * 16 + quad * 4 + r;
#pragma unroll
      for (int nd = 0; nd < 4; nd++) {
        const int d = nd * 16 + l15;
        ob[(((size_t)(b * S_LEN + s)) << 10) + h * 64 + d] =
            (bf16_t)(acc_o[mi][nd][r] * inv);
      }
    }
  }
}

// ---------------------------------------------------------------------------
extern "C" void kernel_launch(void* const* d_in, const int* in_sizes, int n_in,
                              void* d_out, int out_size, void* d_ws, size_t ws_size,
                              hipStream_t stream)
{
  (void)in_sizes; (void)n_in; (void)out_size; (void)ws_size;
  const float* Q  = (const float*)d_in[0];
  const float* K  = (const float*)d_in[1];
  const float* V  = (const float*)d_in[2];
  const float* Wq = (const float*)d_in[4];
  const float* bq = (const float*)d_in[5];
  const float* Wk = (const float*)d_in[6];
  const float* bk = (const float*)d_in[7];
  const float* Wv = (const float*)d_in[8];
  const float* bv = (const float*)d_in[9];
  const float* Wo = (const float*)d_in[10];
  const float* bo = (const float*)d_in[11];
  float* out = (float*)d_out;

  const size_t NELT = (size_t)MROWS * D_MODEL;
  bf16_t* qp   = (bf16_t*)d_ws;                     // [B,H,S,DK] (pre-scaled)
  bf16_t* kp   = qp + NELT;                         // [B,H,S,DK]
  bf16_t* vtp  = kp + NELT;                         // [B,H,DK,S]
  bf16_t* obuf = vtp + NELT;                        // [B,S,H*DK]
  bf16_t* wqt  = obuf + NELT;
  bf16_t* wkt  = wqt + (size_t)D_MODEL * D_MODEL;
  bf16_t* wvt  = wkt + (size_t)D_MODEL * D_MODEL;
  bf16_t* wot  = wvt + (size_t)D_MODEL * D_MODEL;

  dim3 blk(256);
  transpose_w_kernel<<<dim3(16, 16, 4), blk, 0, stream>>>(
      Wq, Wk, Wv, Wo, wqt, wkt, wvt, wot);

  proj_kernel<<<dim3(D_MODEL / 128, MROWS / 128, 3), blk, 0, stream>>>(
      Q, K, V, wqt, wkt, wvt, bq, bk, bv, qp, kp, vtp);

  attn_kernel<<<dim3(S_LEN / 128, BATCH * NHEAD), blk, 0, stream>>>(
      qp, kp, vtp, obuf);

  out_gemm_kernel<<<dim3(D_MODEL / 128, MROWS / 128), blk, 0, stream>>>(
      obuf, wot, bo, out);
}

// Round 3
// 475.026 us; speedup vs baseline: 1.3396x; 1.1224x over previous
//
#include <hip/hip_runtime.h>

typedef __bf16 bf16_t;
typedef __bf16 bf16x8 __attribute__((ext_vector_type(8)));
typedef __bf16 bf16x4 __attribute__((ext_vector_type(4)));
typedef float  floatx4 __attribute__((ext_vector_type(4)));

#define D_MODEL 1024
#define S_LEN   2048
#define NHEAD   16
#define DK      64
#define BATCH   4
#define MROWS   (BATCH * S_LEN)   // 8192
// 1/sqrt(64) * log2(e): fold into Q so scores arrive in exp2 domain
#define QSCALE  0.18033688011112042f

__device__ __forceinline__ void load_lds16(const void* gsrc, void* ldst) {
  __builtin_amdgcn_global_load_lds(
      (const __attribute__((address_space(1))) void*)gsrc,
      (__attribute__((address_space(3))) void*)ldst, 16, 0, 0);
}

// ---------------------------------------------------------------------------
// Fused weight transpose + fp32->bf16 for all 4 weights (z selects).
// ---------------------------------------------------------------------------
__global__ __launch_bounds__(256)
void transpose_w_kernel(const float* __restrict__ W0, const float* __restrict__ W1,
                        const float* __restrict__ W2, const float* __restrict__ W3,
                        bf16_t* __restrict__ T0, bf16_t* __restrict__ T1,
                        bf16_t* __restrict__ T2, bf16_t* __restrict__ T3)
{
  const int z = blockIdx.z;
  const float* W = z == 0 ? W0 : (z == 1 ? W1 : (z == 2 ? W2 : W3));
  bf16_t* Wt     = z == 0 ? T0 : (z == 1 ? T1 : (z == 2 ? T2 : T3));

  __shared__ float tile[64][65];
  const int x0 = blockIdx.x * 64;         // n
  const int y0 = blockIdx.y * 64;         // k
  const int tid = threadIdx.x;
  const int r = tid >> 4;
  const int c = (tid & 15) << 2;
#pragma unroll
  for (int p = 0; p < 4; p++) {
    floatx4 v = *(const floatx4*)&W[(size_t)(y0 + p * 16 + r) * D_MODEL + x0 + c];
    tile[p * 16 + r][c + 0] = v[0];
    tile[p * 16 + r][c + 1] = v[1];
    tile[p * 16 + r][c + 2] = v[2];
    tile[p * 16 + r][c + 3] = v[3];
  }
  __syncthreads();
#pragma unroll
  for (int p = 0; p < 4; p++) {
    int row = p * 16 + r;
    bf16x4 o;
    o[0] = (bf16_t)tile[c + 0][row];
    o[1] = (bf16_t)tile[c + 1][row];
    o[2] = (bf16_t)tile[c + 2][row];
    o[3] = (bf16_t)tile[c + 3][row];
    *(bf16x4*)&Wt[(size_t)(x0 + row) * D_MODEL + y0 + c] = o;
  }
}

// ---------------------------------------------------------------------------
// Fused Q/K/V projection GEMM (z = 0/1/2). A fp32 staged+converted via regs;
// W (bf16, pre-transposed [N][K]) staged via global_load_lds w/ XOR swizzle.
// z=0: q out [B,H,S,DK] * QSCALE | z=1: k out [B,H,S,DK] | z=2: v^T [B,H,DK,S]
// ---------------------------------------------------------------------------
__global__ __launch_bounds__(256)
void proj_kernel(const float* __restrict__ Qi, const float* __restrict__ Ki,
                 const float* __restrict__ Vi,
                 const bf16_t* __restrict__ wq, const bf16_t* __restrict__ wk,
                 const bf16_t* __restrict__ wv,
                 const float* __restrict__ bqp, const float* __restrict__ bkp,
                 const float* __restrict__ bvp,
                 bf16_t* __restrict__ qo, bf16_t* __restrict__ ko,
                 bf16_t* __restrict__ vo)
{
  const int z = blockIdx.z;
  const float* A    = z == 0 ? Qi : (z == 1 ? Ki : Vi);
  const bf16_t* Wt  = z == 0 ? wq : (z == 1 ? wk : wv);
  const float* bias = z == 0 ? bqp : (z == 1 ? bkp : bvp);

  __shared__ bf16_t As[128 * 40];   // padded LD=40 (reg-staged, fp32 convert)
  __shared__ bf16_t Bs[128 * 32];   // linear, global_load_lds + XOR swizzle

  const int m0 = blockIdx.y << 7;
  const int n0 = blockIdx.x << 7;
  const int tid = threadIdx.x;
  const int lane = tid & 63;
  const int w = tid >> 6;
  const int l15 = lane & 15;
  const int quad = lane >> 4;
  const int wy = (w >> 1) << 6;
  const int wx = (w & 1) << 6;
  const int w64 = w << 6;

  floatx4 acc[4][4];
#pragma unroll
  for (int i = 0; i < 4; i++)
#pragma unroll
    for (int j = 0; j < 4; j++)
#pragma unroll
      for (int r = 0; r < 4; r++) acc[i][j][r] = 0.0f;

  for (int kt = 0; kt < 32; kt++) {
    const int k0 = kt << 5;
    __syncthreads();
    // B via global_load_lds, chunk slot s holds (row=s>>2, kc=(s&3)^(row&3))
#pragma unroll
    for (int p = 0; p < 2; p++) {
      int slot = p * 256 + w64 + lane;
      int row = slot >> 2;
      int kc = (slot & 3) ^ (row & 3);
      load_lds16(&Wt[(size_t)(n0 + row) * D_MODEL + k0 + (kc << 3)],
                 &Bs[(size_t)(p * 256 + w64) << 3]);
    }
    // A fp32 -> bf16 via regs
#pragma unroll
    for (int p = 0; p < 4; p++) {
      int idx = p * 256 + tid;
      int r = idx >> 3, c = idx & 7;
      floatx4 v = *(const floatx4*)&A[(size_t)(m0 + r) * D_MODEL + k0 + (c << 2)];
      bf16x4 o;
      o[0] = (bf16_t)v[0]; o[1] = (bf16_t)v[1];
      o[2] = (bf16_t)v[2]; o[3] = (bf16_t)v[3];
      *(bf16x4*)&As[r * 40 + (c << 2)] = o;
    }
    __syncthreads();

    bf16x8 af[4], bfv[4];
#pragma unroll
    for (int mi = 0; mi < 4; mi++) {
      int m = wy + mi * 16 + l15;
      af[mi] = *(const bf16x8*)&As[m * 40 + (quad << 3)];
    }
#pragma unroll
    for (int ni = 0; ni < 4; ni++) {
      int n = wx + ni * 16 + l15;
      bfv[ni] = *(const bf16x8*)&Bs[n * 32 + ((quad ^ (n & 3)) << 3)];
    }
#pragma unroll
    for (int mi = 0; mi < 4; mi++)
#pragma unroll
      for (int ni = 0; ni < 4; ni++)
        acc[mi][ni] = __builtin_amdgcn_mfma_f32_16x16x32_bf16(
            af[mi], bfv[ni], acc[mi][ni], 0, 0, 0);
  }

  const float scl = (z == 0) ? QSCALE : 1.0f;
  bf16_t* outp = z == 0 ? qo : (z == 1 ? ko : vo);
#pragma unroll
  for (int mi = 0; mi < 4; mi++) {
#pragma unroll
    for (int ni = 0; ni < 4; ni++) {
      const int nbase = n0 + wx + ni * 16 + l15;
      const float bv = bias[nbase];
      const int h = nbase >> 6, d = nbase & 63;
#pragma unroll
      for (int r = 0; r < 4; r++) {
        const int m = m0 + wy + mi * 16 + quad * 4 + r;
        const int b = m >> 11, s = m & (S_LEN - 1);
        float v = (acc[mi][ni][r] + bv) * scl;
        if (z < 2) {
          outp[((((size_t)(b * NHEAD + h) << 11) + s) << 6) + d] = (bf16_t)v;
        } else {
          outp[((((size_t)(b * NHEAD + h) << 6) + d) << 11) + s] = (bf16_t)v;
        }
      }
    }
  }
}

// ---------------------------------------------------------------------------
// Output GEMM: out = obuf(bf16) @ Wo + bo, fp32 out. Both operands via
// global_load_lds with XOR swizzle.
// ---------------------------------------------------------------------------
__global__ __launch_bounds__(256)
void out_gemm_kernel(const bf16_t* __restrict__ A, const bf16_t* __restrict__ Wt,
                     const float* __restrict__ bias, float* __restrict__ out)
{
  __shared__ bf16_t As[128 * 32];
  __shared__ bf16_t Bs[128 * 32];
  const int m0 = blockIdx.y << 7;
  const int n0 = blockIdx.x << 7;
  const int tid = threadIdx.x;
  const int lane = tid & 63;
  const int w = tid >> 6;
  const int l15 = lane & 15;
  const int quad = lane >> 4;
  const int wy = (w >> 1) << 6;
  const int wx = (w & 1) << 6;
  const int w64 = w << 6;

  floatx4 acc[4][4];
#pragma unroll
  for (int i = 0; i < 4; i++)
#pragma unroll
    for (int j = 0; j < 4; j++)
#pragma unroll
      for (int r = 0; r < 4; r++) acc[i][j][r] = 0.0f;

  for (int kt = 0; kt < 32; kt++) {
    const int k0 = kt << 5;
    __syncthreads();
#pragma unroll
    for (int p = 0; p < 2; p++) {
      int slot = p * 256 + w64 + lane;
      int row = slot >> 2;
      int kc = (slot & 3) ^ (row & 3);
      load_lds16(&A[(size_t)(m0 + row) * D_MODEL + k0 + (kc << 3)],
                 &As[(size_t)(p * 256 + w64) << 3]);
      load_lds16(&Wt[(size_t)(n0 + row) * D_MODEL + k0 + (kc << 3)],
                 &Bs[(size_t)(p * 256 + w64) << 3]);
    }
    __syncthreads();

    bf16x8 af[4], bfv[4];
#pragma unroll
    for (int mi = 0; mi < 4; mi++) {
      int m = wy + mi * 16 + l15;
      af[mi] = *(const bf16x8*)&As[m * 32 + ((quad ^ (m & 3)) << 3)];
    }
#pragma unroll
    for (int ni = 0; ni < 4; ni++) {
      int n = wx + ni * 16 + l15;
      bfv[ni] = *(const bf16x8*)&Bs[n * 32 + ((quad ^ (n & 3)) << 3)];
    }
#pragma unroll
    for (int mi = 0; mi < 4; mi++)
#pragma unroll
      for (int ni = 0; ni < 4; ni++)
        acc[mi][ni] = __builtin_amdgcn_mfma_f32_16x16x32_bf16(
            af[mi], bfv[ni], acc[mi][ni], 0, 0, 0);
  }

#pragma unroll
  for (int mi = 0; mi < 4; mi++) {
#pragma unroll
    for (int ni = 0; ni < 4; ni++) {
      const int nbase = n0 + wx + ni * 16 + l15;
      const float bv = bias[nbase];
#pragma unroll
      for (int r = 0; r < 4; r++) {
        const int m = m0 + wy + mi * 16 + quad * 4 + r;
        out[((size_t)m << 10) + nbase] = acc[mi][ni][r] + bv;
      }
    }
  }
}

// ---------------------------------------------------------------------------
// Causal flash attention, double-buffered LDS K/V staging via global_load_lds.
// Block = 128 q-rows of one (b,h); 4 waves x 32 q-rows. K-tile = 64 keys.
// Pipeline per tile: sync (drains tile-kb loads, issued one body earlier) ->
// read K frags -> issue gll for tile kb+1 into the other buffer -> QK MFMA ->
// softmax -> P LDS roundtrip -> PV MFMA. Loads overlap the ~800-cyc body.
// XOR chunk swizzle (global-side, since gll LDS dests are lane-contiguous)
// makes frag ds_read_b128s 2-way (free). Loop count is block-uniform
// (nkb = 2*qt+2, even); fully-masked surplus tiles contribute exactly 0.
// ---------------------------------------------------------------------------
__global__ __launch_bounds__(256)
void attn_kernel(const bf16_t* __restrict__ qp, const bf16_t* __restrict__ kp,
                 const bf16_t* __restrict__ vtp, bf16_t* __restrict__ ob)
{
  __shared__ bf16_t Kt0[64 * 64];
  __shared__ bf16_t Kt1[64 * 64];
  __shared__ bf16_t Vt0[64 * 64];
  __shared__ bf16_t Vt1[64 * 64];
  __shared__ bf16_t Ps[4][32][68];

  const int qt = 15 - blockIdx.x;          // big blocks dispatched first
  const int bh = blockIdx.y;
  const int q0 = qt << 7;
  const int tid = threadIdx.x;
  const int w = tid >> 6;
  const int lane = tid & 63;
  const int l15 = lane & 15;
  const int quad = lane >> 4;
  const int qbase = q0 + w * 32;

  const bf16_t* Qh = qp + ((size_t)bh << 17);
  const bf16_t* Kh = kp + ((size_t)bh << 17);
  const bf16_t* Vh = vtp + ((size_t)bh << 17);   // [64][2048]

  bf16x8 qf[2][2];
#pragma unroll
  for (int mi = 0; mi < 2; mi++)
#pragma unroll
    for (int ks = 0; ks < 2; ks++)
      qf[mi][ks] = *(const bf16x8*)&Qh[(size_t)(qbase + mi * 16 + l15) * DK +
                                       ks * 32 + (quad << 3)];

  bf16x8 ones;
#pragma unroll
  for (int i = 0; i < 8; i++) ones[i] = (bf16_t)1.0f;

  floatx4 acc_o[2][4];
  float m_i[2][4], l_i[2][4];
#pragma unroll
  for (int mi = 0; mi < 2; mi++)
#pragma unroll
    for (int r = 0; r < 4; r++) { m_i[mi][r] = -1e30f; l_i[mi][r] = 0.0f; }
#pragma unroll
  for (int mi = 0; mi < 2; mi++)
#pragma unroll
    for (int nd = 0; nd < 4; nd++)
#pragma unroll
      for (int r = 0; r < 4; r++) acc_o[mi][nd][r] = 0.0f;

  const int nkb = (qt << 1) + 2;           // block-uniform, even

  // Cooperative stage of one 64-key K tile + V^T tile (4 gll / wave).
  // Slot s (0..511): row=s>>3, stored chunk cp=s&7 holds global chunk
  // c=cp^(row&7); each chunk is 8 bf16 = 16B.
  auto stage = [&](int k0s, bf16_t* dK, bf16_t* dV) {
#pragma unroll
    for (int p = 0; p < 2; p++) {
      const int sbase = (w << 7) + (p << 6);
      const int slot = sbase + lane;
      const int row = slot >> 3;
      const int c = (slot & 7) ^ (row & 7);
      load_lds16(&Kh[((size_t)(k0s + row) << 6) + (c << 3)], &dK[sbase << 3]);
      load_lds16(&Vh[((size_t)row << 11) + k0s + (c << 3)], &dV[sbase << 3]);
    }
  };

  auto body = [&](int kb, const bf16_t* curK, const bf16_t* curV,
                  bf16_t* nxtK, bf16_t* nxtV) {
    const int k0 = kb << 6;
    __syncthreads();   // drains tile-kb gll (issued one body ago): cheap

    // ---- K fragments from LDS (swizzled) ----
    bf16x8 bk[2][4];
#pragma unroll
    for (int ks = 0; ks < 2; ks++)
#pragma unroll
      for (int ni = 0; ni < 4; ni++) {
        const int row = ni * 16 + l15;
        const int cp = ((ks << 2) + quad) ^ (row & 7);
        bk[ks][ni] = *(const bf16x8*)&curK[(row << 6) + (cp << 3)];
      }

    // ---- prefetch next tile while we compute this one ----
    if (kb + 1 < nkb) stage((kb + 1) << 6, nxtK, nxtV);

    // ---- S = Q K^T ----
    floatx4 acc_s[2][4];
#pragma unroll
    for (int mi = 0; mi < 2; mi++)
#pragma unroll
      for (int ni = 0; ni < 4; ni++)
#pragma unroll
        for (int r = 0; r < 4; r++) acc_s[mi][ni][r] = 0.0f;
#pragma unroll
    for (int ks = 0; ks < 2; ks++)
#pragma unroll
      for (int mi = 0; mi < 2; mi++)
#pragma unroll
        for (int ni = 0; ni < 4; ni++)
          acc_s[mi][ni] = __builtin_amdgcn_mfma_f32_16x16x32_bf16(
              qf[mi][ks], bk[ks][ni], acc_s[mi][ni], 0, 0, 0);

    // ---- causal mask: only tiles touching the diagonal ----
    if (k0 + 63 > qbase) {
#pragma unroll
      for (int mi = 0; mi < 2; mi++)
#pragma unroll
        for (int ni = 0; ni < 4; ni++) {
          const int key = k0 + ni * 16 + l15;
#pragma unroll
          for (int r = 0; r < 4; r++)
            if (key > qbase + mi * 16 + quad * 4 + r) acc_s[mi][ni][r] = -1e30f;
        }
    }

    // ---- rowmax -> alpha, m update ----
    float alpha[2][4];
#pragma unroll
    for (int mi = 0; mi < 2; mi++) {
#pragma unroll
      for (int r = 0; r < 4; r++) {
        float v = fmaxf(fmaxf(acc_s[mi][0][r], acc_s[mi][1][r]),
                        fmaxf(acc_s[mi][2][r], acc_s[mi][3][r]));
        v = fmaxf(v, __shfl_xor(v, 1));
        v = fmaxf(v, __shfl_xor(v, 2));
        v = fmaxf(v, __shfl_xor(v, 4));
        v = fmaxf(v, __shfl_xor(v, 8));
        float mn = fmaxf(m_i[mi][r], v);
        alpha[mi][r] = __builtin_amdgcn_exp2f(m_i[mi][r] - mn);
        m_i[mi][r] = mn;
      }
    }

    // ---- P = exp2(S - m) -> per-wave LDS (C-layout -> A-layout) ----
#pragma unroll
    for (int mi = 0; mi < 2; mi++)
#pragma unroll
      for (int ni = 0; ni < 4; ni++)
#pragma unroll
        for (int r = 0; r < 4; r++) {
          float p = __builtin_amdgcn_exp2f(acc_s[mi][ni][r] - m_i[mi][r]);
          Ps[w][mi * 16 + quad * 4 + r][ni * 16 + l15] = (bf16_t)p;
        }

    // ---- rescale O ----
#pragma unroll
    for (int mi = 0; mi < 2; mi++)
#pragma unroll
      for (int nd = 0; nd < 4; nd++)
#pragma unroll
        for (int r = 0; r < 4; r++) acc_o[mi][nd][r] *= alpha[mi][r];

    // ---- P back in A-layout; rowsum via ones-MFMA ----
    bf16x8 av[2][2];
#pragma unroll
    for (int mi = 0; mi < 2; mi++)
#pragma unroll
      for (int ks = 0; ks < 2; ks++)
        av[mi][ks] = *(const bf16x8*)&Ps[w][mi * 16 + l15][ks * 32 + (quad << 3)];

    floatx4 acc_l[2];
#pragma unroll
    for (int mi = 0; mi < 2; mi++) {
#pragma unroll
      for (int r = 0; r < 4; r++) acc_l[mi][r] = 0.0f;
#pragma unroll
      for (int ks = 0; ks < 2; ks++)
        acc_l[mi] = __builtin_amdgcn_mfma_f32_16x16x32_bf16(
            av[mi][ks], ones, acc_l[mi], 0, 0, 0);
    }

    // ---- O += P V (V^T frags from LDS, swizzled) ----
#pragma unroll
    for (int ks = 0; ks < 2; ks++) {
      bf16x8 bv[4];
#pragma unroll
      for (int nd = 0; nd < 4; nd++) {
        const int row = nd * 16 + l15;
        const int cp = ((ks << 2) + quad) ^ (row & 7);
        bv[nd] = *(const bf16x8*)&curV[(row << 6) + (cp << 3)];
      }
#pragma unroll
      for (int mi = 0; mi < 2; mi++)
#pragma unroll
        for (int nd = 0; nd < 4; nd++)
          acc_o[mi][nd] = __builtin_amdgcn_mfma_f32_16x16x32_bf16(
              av[mi][ks], bv[nd], acc_o[mi][nd], 0, 0, 0);
    }

#pragma unroll
    for (int mi = 0; mi < 2; mi++)
#pragma unroll
      for (int r = 0; r < 4; r++)
        l_i[mi][r] = l_i[mi][r] * alpha[mi][r] + acc_l[mi][r];
  };

  stage(0, Kt0, Vt0);
  for (int kb = 0; kb < nkb; kb += 2) {
    body(kb,     Kt0, Vt0, Kt1, Vt1);
    body(kb + 1, Kt1, Vt1, Kt0, Vt0);
  }

  // ---- epilogue: O /= l, write [B, S, H*64] bf16 ----
  const int b = bh >> 4, h = bh & 15;
#pragma unroll
  for (int mi = 0; mi < 2; mi++) {
#pragma unroll
    for (int r = 0; r < 4; r++) {
      const float inv = 1.0f / l_i[mi][r];
      const int s = qbase + mi * 16 + quad * 4 + r;
#pragma unroll
      for (int nd = 0; nd < 4; nd++) {
        const int d = nd * 16 + l15;
        ob[(((size_t)(b * S_LEN + s)) << 10) + h * 64 + d] =
            (bf16_t)(acc_o[mi][nd][r] * inv);
      }
    }
  }
}

// ---------------------------------------------------------------------------
extern "C" void kernel_launch(void* const* d_in, const int* in_sizes, int n_in,
                              void* d_out, int out_size, void* d_ws, size_t ws_size,
                              hipStream_t stream)
{
  (void)in_sizes; (void)n_in; (void)out_size; (void)ws_size;
  const float* Q  = (const float*)d_in[0];
  const float* K  = (const float*)d_in[1];
  const float* V  = (const float*)d_in[2];
  const float* Wq = (const float*)d_in[4];
  const float* bq = (const float*)d_in[5];
  const float* Wk = (const float*)d_in[6];
  const float* bk = (const float*)d_in[7];
  const float* Wv = (const float*)d_in[8];
  const float* bv = (const float*)d_in[9];
  const float* Wo = (const float*)d_in[10];
  const float* bo = (const float*)d_in[11];
  float* out = (float*)d_out;

  const size_t NELT = (size_t)MROWS * D_MODEL;
  bf16_t* qp   = (bf16_t*)d_ws;                     // [B,H,S,DK] (pre-scaled)
  bf16_t* kp   = qp + NELT;                         // [B,H,S,DK]
  bf16_t* vtp  = kp + NELT;                         // [B,H,DK,S]
  bf16_t* obuf = vtp + NELT;                        // [B,S,H*DK]
  bf16_t* wqt  = obuf + NELT;
  bf16_t* wkt  = wqt + (size_t)D_MODEL * D_MODEL;
  bf16_t* wvt  = wkt + (size_t)D_MODEL * D_MODEL;
  bf16_t* wot  = wvt + (size_t)D_MODEL * D_MODEL;

  dim3 blk(256);
  transpose_w_kernel<<<dim3(16, 16, 4), blk, 0, stream>>>(
      Wq, Wk, Wv, Wo, wqt, wkt, wvt, wot);

  proj_kernel<<<dim3(D_MODEL / 128, MROWS / 128, 3), blk, 0, stream>>>(
      Q, K, V, wqt, wkt, wvt, bq, bk, bv, qp, kp, vtp);

  attn_kernel<<<dim3(S_LEN / 128, BATCH * NHEAD), blk, 0, stream>>>(
      qp, kp, vtp, obuf);

  out_gemm_kernel<<<dim3(D_MODEL / 128, MROWS / 128), blk, 0, stream>>>(
      obuf, wot, bo, out);
}

// Round 4
// 452.138 us; speedup vs baseline: 1.4075x; 1.0506x over previous
//
#include <hip/hip_runtime.h>

typedef __bf16 bf16_t;
typedef __bf16 bf16x8 __attribute__((ext_vector_type(8)));
typedef __bf16 bf16x4 __attribute__((ext_vector_type(4)));
typedef float  floatx4 __attribute__((ext_vector_type(4)));

#define D_MODEL 1024
#define S_LEN   2048
#define NHEAD   16
#define DK      64
#define BATCH   4
#define MROWS   (BATCH * S_LEN)   // 8192
// 1/sqrt(64) * log2(e): fold into Q so scores arrive in exp2 domain
#define QSCALE  0.18033688011112042f

__device__ __forceinline__ void load_lds16(const void* gsrc, void* ldst) {
  __builtin_amdgcn_global_load_lds(
      (const __attribute__((address_space(1))) void*)gsrc,
      (__attribute__((address_space(3))) void*)ldst, 16, 0, 0);
}

__device__ __forceinline__ unsigned pack_bf16(float a, float b) {
  union { bf16_t h[2]; unsigned u; } t;
  t.h[0] = (bf16_t)a; t.h[1] = (bf16_t)b;
  return t.u;
}

__device__ __forceinline__ float bperm_f(int addr, float v) {
  union { float f; int i; } in, out;
  in.f = v;
  out.i = __builtin_amdgcn_ds_bpermute(addr, in.i);
  return out.f;
}

// ---------------------------------------------------------------------------
// Fused weight transpose + fp32->bf16 for all 4 weights (z selects).
// ---------------------------------------------------------------------------
__global__ __launch_bounds__(256)
void transpose_w_kernel(const float* __restrict__ W0, const float* __restrict__ W1,
                        const float* __restrict__ W2, const float* __restrict__ W3,
                        bf16_t* __restrict__ T0, bf16_t* __restrict__ T1,
                        bf16_t* __restrict__ T2, bf16_t* __restrict__ T3)
{
  const int z = blockIdx.z;
  const float* W = z == 0 ? W0 : (z == 1 ? W1 : (z == 2 ? W2 : W3));
  bf16_t* Wt     = z == 0 ? T0 : (z == 1 ? T1 : (z == 2 ? T2 : T3));

  __shared__ float tile[64][65];
  const int x0 = blockIdx.x * 64;         // n
  const int y0 = blockIdx.y * 64;         // k
  const int tid = threadIdx.x;
  const int r = tid >> 4;
  const int c = (tid & 15) << 2;
#pragma unroll
  for (int p = 0; p < 4; p++) {
    floatx4 v = *(const floatx4*)&W[(size_t)(y0 + p * 16 + r) * D_MODEL + x0 + c];
    tile[p * 16 + r][c + 0] = v[0];
    tile[p * 16 + r][c + 1] = v[1];
    tile[p * 16 + r][c + 2] = v[2];
    tile[p * 16 + r][c + 3] = v[3];
  }
  __syncthreads();
#pragma unroll
  for (int p = 0; p < 4; p++) {
    int row = p * 16 + r;
    bf16x4 o;
    o[0] = (bf16_t)tile[c + 0][row];
    o[1] = (bf16_t)tile[c + 1][row];
    o[2] = (bf16_t)tile[c + 2][row];
    o[3] = (bf16_t)tile[c + 3][row];
    *(bf16x4*)&Wt[(size_t)(x0 + row) * D_MODEL + y0 + c] = o;
  }
}

// ---------------------------------------------------------------------------
// fp32 -> bf16 elementwise convert (8 elems/thread, 4096 blocks for 8M elems)
// ---------------------------------------------------------------------------
__global__ __launch_bounds__(256)
void cvt_kernel(const float* __restrict__ src, bf16_t* __restrict__ dst)
{
  const size_t i = ((size_t)blockIdx.x * 256 + threadIdx.x) * 8;
  floatx4 a = *(const floatx4*)&src[i];
  floatx4 b = *(const floatx4*)&src[i + 4];
  bf16x8 o;
  o[0] = (bf16_t)a[0]; o[1] = (bf16_t)a[1];
  o[2] = (bf16_t)a[2]; o[3] = (bf16_t)a[3];
  o[4] = (bf16_t)b[0]; o[5] = (bf16_t)b[1];
  o[6] = (bf16_t)b[2]; o[7] = (bf16_t)b[3];
  *(bf16x8*)&dst[i] = o;
}

// ---------------------------------------------------------------------------
// Projection GEMM (m97-style: both operands via global_load_lds + XOR swizzle)
// out = (A @ Wt^T + bias) * scl, bf16. TRANS 0: [B,H,S,DK]; 1: [B,H,DK,S].
// ---------------------------------------------------------------------------
template<int TRANS>
__global__ __launch_bounds__(256)
void proj_kernel(const bf16_t* __restrict__ A, const bf16_t* __restrict__ Wt,
                 const float* __restrict__ bias, bf16_t* __restrict__ outp,
                 float scl)
{
  __shared__ bf16_t As[128 * 32];
  __shared__ bf16_t Bs[128 * 32];
  const int m0 = blockIdx.y << 7;
  const int n0 = blockIdx.x << 7;
  const int tid = threadIdx.x;
  const int lane = tid & 63;
  const int w = tid >> 6;
  const int l15 = lane & 15;
  const int quad = lane >> 4;
  const int wy = (w >> 1) << 6;
  const int wx = (w & 1) << 6;
  const int w64 = w << 6;

  floatx4 acc[4][4];
#pragma unroll
  for (int i = 0; i < 4; i++)
#pragma unroll
    for (int j = 0; j < 4; j++)
#pragma unroll
      for (int r = 0; r < 4; r++) acc[i][j][r] = 0.0f;

  for (int kt = 0; kt < 32; kt++) {
    const int k0 = kt << 5;
    __syncthreads();
#pragma unroll
    for (int p = 0; p < 2; p++) {
      int slot = p * 256 + w64 + lane;
      int row = slot >> 2;
      int kc = (slot & 3) ^ (row & 3);
      load_lds16(&A[(size_t)(m0 + row) * D_MODEL + k0 + (kc << 3)],
                 &As[(size_t)(p * 256 + w64) << 3]);
      load_lds16(&Wt[(size_t)(n0 + row) * D_MODEL + k0 + (kc << 3)],
                 &Bs[(size_t)(p * 256 + w64) << 3]);
    }
    __syncthreads();

    bf16x8 af[4], bfv[4];
#pragma unroll
    for (int mi = 0; mi < 4; mi++) {
      int m = wy + mi * 16 + l15;
      af[mi] = *(const bf16x8*)&As[m * 32 + ((quad ^ (m & 3)) << 3)];
    }
#pragma unroll
    for (int ni = 0; ni < 4; ni++) {
      int n = wx + ni * 16 + l15;
      bfv[ni] = *(const bf16x8*)&Bs[n * 32 + ((quad ^ (n & 3)) << 3)];
    }
#pragma unroll
    for (int mi = 0; mi < 4; mi++)
#pragma unroll
      for (int ni = 0; ni < 4; ni++)
        acc[mi][ni] = __builtin_amdgcn_mfma_f32_16x16x32_bf16(
            af[mi], bfv[ni], acc[mi][ni], 0, 0, 0);
  }

#pragma unroll
  for (int mi = 0; mi < 4; mi++) {
#pragma unroll
    for (int ni = 0; ni < 4; ni++) {
      const int nbase = n0 + wx + ni * 16 + l15;
      const float bv = bias[nbase];
      const int h = nbase >> 6, d = nbase & 63;
#pragma unroll
      for (int r = 0; r < 4; r++) {
        const int m = m0 + wy + mi * 16 + quad * 4 + r;
        const int b = m >> 11, s = m & (S_LEN - 1);
        float v = (acc[mi][ni][r] + bv) * scl;
        if constexpr (TRANS == 0) {
          outp[((((size_t)(b * NHEAD + h) << 11) + s) << 6) + d] = (bf16_t)v;
        } else {
          outp[((((size_t)(b * NHEAD + h) << 6) + d) << 11) + s] = (bf16_t)v;
        }
      }
    }
  }
}

// ---------------------------------------------------------------------------
// Output GEMM: out = obuf(bf16) @ Wo + bo, fp32 out.
// ---------------------------------------------------------------------------
__global__ __launch_bounds__(256)
void out_gemm_kernel(const bf16_t* __restrict__ A, const bf16_t* __restrict__ Wt,
                     const float* __restrict__ bias, float* __restrict__ out)
{
  __shared__ bf16_t As[128 * 32];
  __shared__ bf16_t Bs[128 * 32];
  const int m0 = blockIdx.y << 7;
  const int n0 = blockIdx.x << 7;
  const int tid = threadIdx.x;
  const int lane = tid & 63;
  const int w = tid >> 6;
  const int l15 = lane & 15;
  const int quad = lane >> 4;
  const int wy = (w >> 1) << 6;
  const int wx = (w & 1) << 6;
  const int w64 = w << 6;

  floatx4 acc[4][4];
#pragma unroll
  for (int i = 0; i < 4; i++)
#pragma unroll
    for (int j = 0; j < 4; j++)
#pragma unroll
      for (int r = 0; r < 4; r++) acc[i][j][r] = 0.0f;

  for (int kt = 0; kt < 32; kt++) {
    const int k0 = kt << 5;
    __syncthreads();
#pragma unroll
    for (int p = 0; p < 2; p++) {
      int slot = p * 256 + w64 + lane;
      int row = slot >> 2;
      int kc = (slot & 3) ^ (row & 3);
      load_lds16(&A[(size_t)(m0 + row) * D_MODEL + k0 + (kc << 3)],
                 &As[(size_t)(p * 256 + w64) << 3]);
      load_lds16(&Wt[(size_t)(n0 + row) * D_MODEL + k0 + (kc << 3)],
                 &Bs[(size_t)(p * 256 + w64) << 3]);
    }
    __syncthreads();

    bf16x8 af[4], bfv[4];
#pragma unroll
    for (int mi = 0; mi < 4; mi++) {
      int m = wy + mi * 16 + l15;
      af[mi] = *(const bf16x8*)&As[m * 32 + ((quad ^ (m & 3)) << 3)];
    }
#pragma unroll
    for (int ni = 0; ni < 4; ni++) {
      int n = wx + ni * 16 + l15;
      bfv[ni] = *(const bf16x8*)&Bs[n * 32 + ((quad ^ (n & 3)) << 3)];
    }
#pragma unroll
    for (int mi = 0; mi < 4; mi++)
#pragma unroll
      for (int ni = 0; ni < 4; ni++)
        acc[mi][ni] = __builtin_amdgcn_mfma_f32_16x16x32_bf16(
            af[mi], bfv[ni], acc[mi][ni], 0, 0, 0);
  }

#pragma unroll
  for (int mi = 0; mi < 4; mi++) {
#pragma unroll
    for (int ni = 0; ni < 4; ni++) {
      const int nbase = n0 + wx + ni * 16 + l15;
      const float bv = bias[nbase];
#pragma unroll
      for (int r = 0; r < 4; r++) {
        const int m = m0 + wy + mi * 16 + quad * 4 + r;
        out[((size_t)m << 10) + nbase] = acc[mi][ni][r] + bv;
      }
    }
  }
}

// ---------------------------------------------------------------------------
// Causal flash attention, S^T formulation.
// S^T = MFMA(A=K_frag, B=Q_frag) -> D[m=key][n=q]: lane owns whole q-rows
// (q = lane&15): rowmax/rowsum are in-register + 2 shuffles. P exits in
// C-layout and is regrouped into the PV A-operand layout purely in registers
// via ds_bpermute (no LDS roundtrip, no Ps array -> LDS = 32 KB).
// alpha / 1/l hop to the O C-layout rows via 8 bpermutes.
// K/V staged double-buffered via global_load_lds (r3-verified addressing).
// ---------------------------------------------------------------------------
__global__ __launch_bounds__(256)
void attn_kernel(const bf16_t* __restrict__ qp, const bf16_t* __restrict__ kp,
                 const bf16_t* __restrict__ vtp, bf16_t* __restrict__ ob)
{
  __shared__ bf16_t Kt0[64 * 64];
  __shared__ bf16_t Kt1[64 * 64];
  __shared__ bf16_t Vt0[64 * 64];
  __shared__ bf16_t Vt1[64 * 64];

  const int qt = 15 - blockIdx.x;          // big blocks dispatched first
  const int bh = blockIdx.y;
  const int q0 = qt << 7;
  const int tid = threadIdx.x;
  const int w = tid >> 6;
  const int lane = tid & 63;
  const int l15 = lane & 15;
  const int quad = lane >> 4;
  const int qbase = q0 + w * 32;

  const bf16_t* Qh = qp + ((size_t)bh << 17);
  const bf16_t* Kh = kp + ((size_t)bh << 17);
  const bf16_t* Vh = vtp + ((size_t)bh << 17);   // [64][2048]

  // Q fragments (B-operand of S^T): n=q=l15 (+mi*16), k=d=quad*8+j (+ks*32)
  bf16x8 qf[2][2];
#pragma unroll
  for (int mi = 0; mi < 2; mi++)
#pragma unroll
    for (int ks = 0; ks < 2; ks++)
      qf[mi][ks] = *(const bf16x8*)&Qh[(size_t)(qbase + mi * 16 + l15) * DK +
                                       ks * 32 + (quad << 3)];

  floatx4 acc_o[2][4];
  float m_i[2], l_i[2];    // row q = qbase + mi*16 + l15 (held at l15 lanes)
#pragma unroll
  for (int mi = 0; mi < 2; mi++) { m_i[mi] = -1e30f; l_i[mi] = 0.0f; }
#pragma unroll
  for (int mi = 0; mi < 2; mi++)
#pragma unroll
    for (int nd = 0; nd < 4; nd++)
#pragma unroll
      for (int r = 0; r < 4; r++) acc_o[mi][nd][r] = 0.0f;

  const int nkb = (qt << 1) + 2;           // block-uniform, even

  auto stage = [&](int k0s, bf16_t* dK, bf16_t* dV) {
#pragma unroll
    for (int p = 0; p < 2; p++) {
      const int sbase = (w << 7) + (p << 6);
      const int slot = sbase + lane;
      const int row = slot >> 3;
      const int c = (slot & 7) ^ (row & 7);
      load_lds16(&Kh[((size_t)(k0s + row) << 6) + (c << 3)], &dK[sbase << 3]);
      load_lds16(&Vh[((size_t)row << 11) + k0s + (c << 3)], &dV[sbase << 3]);
    }
  };

  auto body = [&](int kb, const bf16_t* curK, const bf16_t* curV,
                  bf16_t* nxtK, bf16_t* nxtV) {
    const int k0 = kb << 6;
    __syncthreads();   // drains tile-kb gll (issued one body ago)

    // ---- prefetch next tile ----
    if (kb + 1 < nkb) stage((kb + 1) << 6, nxtK, nxtV);

    // ---- K fragments (A-operand of S^T): m=key=l15 (+ni*16), k=d ----
    bf16x8 bk[2][4];
#pragma unroll
    for (int ks = 0; ks < 2; ks++)
#pragma unroll
      for (int ni = 0; ni < 4; ni++) {
        const int row = ni * 16 + l15;
        const int cp = ((ks << 2) + quad) ^ (row & 7);
        bk[ks][ni] = *(const bf16x8*)&curK[(row << 6) + (cp << 3)];
      }

    // ---- S^T = K Q^T: D[m=key][n=q]; lane: q=l15, key=k0+ni*16+quad*4+r ----
    floatx4 st[2][4];
#pragma unroll
    for (int mi = 0; mi < 2; mi++)
#pragma unroll
      for (int ni = 0; ni < 4; ni++)
#pragma unroll
        for (int r = 0; r < 4; r++) st[mi][ni][r] = 0.0f;
#pragma unroll
    for (int ks = 0; ks < 2; ks++)
#pragma unroll
      for (int mi = 0; mi < 2; mi++)
#pragma unroll
        for (int ni = 0; ni < 4; ni++)
          st[mi][ni] = __builtin_amdgcn_mfma_f32_16x16x32_bf16(
              bk[ks][ni], qf[mi][ks], st[mi][ni], 0, 0, 0);

    // ---- causal mask (diag/surplus tiles only) ----
    if (k0 + 63 > qbase) {
#pragma unroll
      for (int mi = 0; mi < 2; mi++) {
        const int qrow = qbase + mi * 16 + l15;
#pragma unroll
        for (int ni = 0; ni < 4; ni++) {
          const int keyb = k0 + ni * 16 + quad * 4;
#pragma unroll
          for (int r = 0; r < 4; r++)
            if (keyb + r > qrow) st[mi][ni][r] = -1e30f;
        }
      }
    }

    // ---- row stats: in-register + 2 shuffles (over quads) ----
    float alpha[2];
#pragma unroll
    for (int mi = 0; mi < 2; mi++) {
      float v = st[mi][0][0];
#pragma unroll
      for (int ni = 0; ni < 4; ni++)
#pragma unroll
        for (int r = 0; r < 4; r++) v = fmaxf(v, st[mi][ni][r]);
      v = fmaxf(v, __shfl_xor(v, 16));
      v = fmaxf(v, __shfl_xor(v, 32));
      float mn = fmaxf(m_i[mi], v);
      alpha[mi] = __builtin_amdgcn_exp2f(m_i[mi] - mn);
      m_i[mi] = mn;
    }

    // ---- P = exp2(S - m): pack to dwords, partial row sums ----
    unsigned pd[2][4][2];
#pragma unroll
    for (int mi = 0; mi < 2; mi++) {
      float s = 0.0f;
#pragma unroll
      for (int c = 0; c < 4; c++)
#pragma unroll
        for (int h = 0; h < 2; h++) {
          float p0 = __builtin_amdgcn_exp2f(st[mi][c][2 * h]     - m_i[mi]);
          float p1 = __builtin_amdgcn_exp2f(st[mi][c][2 * h + 1] - m_i[mi]);
          s += p0 + p1;
          pd[mi][c][h] = pack_bf16(p0, p1);
        }
      s += __shfl_xor(s, 16);
      s += __shfl_xor(s, 32);
      l_i[mi] = l_i[mi] * alpha[mi] + s;
    }

    // ---- broadcast alpha to O C-layout rows (q=quad*4+r) & rescale ----
#pragma unroll
    for (int mi = 0; mi < 2; mi++)
#pragma unroll
      for (int r = 0; r < 4; r++) {
        float ab = bperm_f((quad * 4 + r) << 2, alpha[mi]);
#pragma unroll
        for (int nd = 0; nd < 4; nd++) acc_o[mi][nd][r] *= ab;
      }

    // ---- register exchange: P (C-layout) -> PV A-operand layout ----
    // target dword i of av[mi][ks] = keys ks*32+quad*8+{2i,2i+1}
    //   source lane quad_s=(2*quad+(i>>1))&3, reg pd[ks*2+(quad>>1)][i&1]
    union AV { unsigned u[4]; bf16x8 v; };
    AV av[2][2];
#pragma unroll
    for (int mi = 0; mi < 2; mi++)
#pragma unroll
      for (int ks = 0; ks < 2; ks++)
#pragma unroll
        for (int i = 0; i < 4; i++) {
          const int addr = ((((2 * quad + (i >> 1)) & 3) << 4) | l15) << 2;
          int lo = __builtin_amdgcn_ds_bpermute(addr, (int)pd[mi][ks * 2][i & 1]);
          int hi = __builtin_amdgcn_ds_bpermute(addr, (int)pd[mi][ks * 2 + 1][i & 1]);
          av[mi][ks].u[i] = (unsigned)(quad >= 2 ? hi : lo);
        }

    // ---- O += P V (V^T frags from LDS) ----
#pragma unroll
    for (int ks = 0; ks < 2; ks++) {
      bf16x8 bv[4];
#pragma unroll
      for (int nd = 0; nd < 4; nd++) {
        const int row = nd * 16 + l15;
        const int cp = ((ks << 2) + quad) ^ (row & 7);
        bv[nd] = *(const bf16x8*)&curV[(row << 6) + (cp << 3)];
      }
#pragma unroll
      for (int mi = 0; mi < 2; mi++)
#pragma unroll
        for (int nd = 0; nd < 4; nd++)
          acc_o[mi][nd] = __builtin_amdgcn_mfma_f32_16x16x32_bf16(
              av[mi][ks].v, bv[nd], acc_o[mi][nd], 0, 0, 0);
    }
  };

  stage(0, Kt0, Vt0);
  for (int kb = 0; kb < nkb; kb += 2) {
    body(kb,     Kt0, Vt0, Kt1, Vt1);
    body(kb + 1, Kt1, Vt1, Kt0, Vt0);
  }

  // ---- epilogue: O /= l (broadcast 1/l to C-layout rows), write bf16 ----
  const int b = bh >> 4, h = bh & 15;
  float inv[2];
#pragma unroll
  for (int mi = 0; mi < 2; mi++) inv[mi] = 1.0f / l_i[mi];
#pragma unroll
  for (int mi = 0; mi < 2; mi++) {
#pragma unroll
    for (int r = 0; r < 4; r++) {
      const float linv = bperm_f((quad * 4 + r) << 2, inv[mi]);
      const int s = qbase + mi * 16 + quad * 4 + r;
#pragma unroll
      for (int nd = 0; nd < 4; nd++) {
        const int d = nd * 16 + l15;
        ob[(((size_t)(b * S_LEN + s)) << 10) + h * 64 + d] =
            (bf16_t)(acc_o[mi][nd][r] * linv);
      }
    }
  }
}

// ---------------------------------------------------------------------------
extern "C" void kernel_launch(void* const* d_in, const int* in_sizes, int n_in,
                              void* d_out, int out_size, void* d_ws, size_t ws_size,
                              hipStream_t stream)
{
  (void)in_sizes; (void)n_in; (void)out_size; (void)ws_size;
  const float* Q  = (const float*)d_in[0];
  const float* K  = (const float*)d_in[1];
  const float* V  = (const float*)d_in[2];
  const float* Wq = (const float*)d_in[4];
  const float* bq = (const float*)d_in[5];
  const float* Wk = (const float*)d_in[6];
  const float* bk = (const float*)d_in[7];
  const float* Wv = (const float*)d_in[8];
  const float* bv = (const float*)d_in[9];
  const float* Wo = (const float*)d_in[10];
  const float* bo = (const float*)d_in[11];
  float* out = (float*)d_out;

  const size_t NELT = (size_t)MROWS * D_MODEL;
  bf16_t* qp   = (bf16_t*)d_ws;                     // [B,H,S,DK] (pre-scaled)
  bf16_t* kp   = qp + NELT;                         // [B,H,S,DK]
  bf16_t* vtp  = kp + NELT;                         // [B,H,DK,S]
  bf16_t* obuf = vtp + NELT;                        // [B,S,H*DK]; tmp before attn
  bf16_t* wqt  = obuf + NELT;
  bf16_t* wkt  = wqt + (size_t)D_MODEL * D_MODEL;
  bf16_t* wvt  = wkt + (size_t)D_MODEL * D_MODEL;
  bf16_t* wot  = wvt + (size_t)D_MODEL * D_MODEL;
  bf16_t* tmp  = obuf;   // bf16 input staging; dead before attn writes obuf

  dim3 blk(256);
  transpose_w_kernel<<<dim3(16, 16, 4), blk, 0, stream>>>(
      Wq, Wk, Wv, Wo, wqt, wkt, wvt, wot);

  dim3 gG(D_MODEL / 128, MROWS / 128);              // (8, 64)
  cvt_kernel<<<dim3(4096), blk, 0, stream>>>(Q, tmp);
  proj_kernel<0><<<gG, blk, 0, stream>>>(tmp, wqt, bq, qp, QSCALE);
  cvt_kernel<<<dim3(4096), blk, 0, stream>>>(K, tmp);
  proj_kernel<0><<<gG, blk, 0, stream>>>(tmp, wkt, bk, kp, 1.0f);
  cvt_kernel<<<dim3(4096), blk, 0, stream>>>(V, tmp);
  proj_kernel<1><<<gG, blk, 0, stream>>>(tmp, wvt, bv, vtp, 1.0f);

  attn_kernel<<<dim3(S_LEN / 128, BATCH * NHEAD), blk, 0, stream>>>(
      qp, kp, vtp, obuf);

  out_gemm_kernel<<<gG, blk, 0, stream>>>(obuf, wot, bo, out);
}

// Round 5
// 387.840 us; speedup vs baseline: 1.6408x; 1.1658x over previous
//
#include <hip/hip_runtime.h>

typedef __bf16 bf16_t;
typedef __bf16 bf16x8 __attribute__((ext_vector_type(8)));
typedef __bf16 bf16x4 __attribute__((ext_vector_type(4)));
typedef float  floatx4 __attribute__((ext_vector_type(4)));

#define D_MODEL 1024
#define S_LEN   2048
#define NHEAD   16
#define DK      64
#define BATCH   4
#define MROWS   (BATCH * S_LEN)   // 8192
// 1/sqrt(64) * log2(e): fold into Q so scores arrive in exp2 domain
#define QSCALE  0.18033688011112042f

__device__ __forceinline__ void load_lds16(const void* gsrc, void* ldst) {
  __builtin_amdgcn_global_load_lds(
      (const __attribute__((address_space(1))) void*)gsrc,
      (__attribute__((address_space(3))) void*)ldst, 16, 0, 0);
}

__device__ __forceinline__ unsigned pack_bf16(float a, float b) {
  union { bf16_t h[2]; unsigned u; } t;
  t.h[0] = (bf16_t)a; t.h[1] = (bf16_t)b;
  return t.u;
}

__device__ __forceinline__ float bperm_f(int addr, float v) {
  union { float f; int i; } in, out;
  in.f = v;
  out.i = __builtin_amdgcn_ds_bpermute(addr, in.i);
  return out.f;
}

// ---------------------------------------------------------------------------
// Fused weight transpose + fp32->bf16 for all 4 weights (z selects).
// wqt/wkt/wvt are contiguous -> form a [3072][1024] matrix for the QKV GEMM.
// ---------------------------------------------------------------------------
__global__ __launch_bounds__(256)
void transpose_w_kernel(const float* __restrict__ W0, const float* __restrict__ W1,
                        const float* __restrict__ W2, const float* __restrict__ W3,
                        bf16_t* __restrict__ T0, bf16_t* __restrict__ T1,
                        bf16_t* __restrict__ T2, bf16_t* __restrict__ T3)
{
  const int z = blockIdx.z;
  const float* W = z == 0 ? W0 : (z == 1 ? W1 : (z == 2 ? W2 : W3));
  bf16_t* Wt     = z == 0 ? T0 : (z == 1 ? T1 : (z == 2 ? T2 : T3));

  __shared__ float tile[64][65];
  const int x0 = blockIdx.x * 64;         // n
  const int y0 = blockIdx.y * 64;         // k
  const int tid = threadIdx.x;
  const int r = tid >> 4;
  const int c = (tid & 15) << 2;
#pragma unroll
  for (int p = 0; p < 4; p++) {
    floatx4 v = *(const floatx4*)&W[(size_t)(y0 + p * 16 + r) * D_MODEL + x0 + c];
    tile[p * 16 + r][c + 0] = v[0];
    tile[p * 16 + r][c + 1] = v[1];
    tile[p * 16 + r][c + 2] = v[2];
    tile[p * 16 + r][c + 3] = v[3];
  }
  __syncthreads();
#pragma unroll
  for (int p = 0; p < 4; p++) {
    int row = p * 16 + r;
    bf16x4 o;
    o[0] = (bf16_t)tile[c + 0][row];
    o[1] = (bf16_t)tile[c + 1][row];
    o[2] = (bf16_t)tile[c + 2][row];
    o[3] = (bf16_t)tile[c + 3][row];
    *(bf16x4*)&Wt[(size_t)(x0 + row) * D_MODEL + y0 + c] = o;
  }
}

// ---------------------------------------------------------------------------
// Fused QKV projection: one GEMM, A=[8192,1024] fp32 (VALU-staged+converted),
// B=Wcat [3072][1024] bf16 (contiguous wqt|wkt|wvt) via global_load_lds.
// z = n0>>10 selects weight third / bias / output tensor & layout.
// grid (24, 64) = 1536 blocks.
// ---------------------------------------------------------------------------
__global__ __launch_bounds__(256, 3)
void qkv_kernel(const float* __restrict__ Qi, const float* __restrict__ Ki,
                const float* __restrict__ Vi, const bf16_t* __restrict__ Wcat,
                const float* __restrict__ bq, const float* __restrict__ bk,
                const float* __restrict__ bv,
                bf16_t* __restrict__ qo, bf16_t* __restrict__ ko,
                bf16_t* __restrict__ vo)
{
  __shared__ bf16_t As[128 * 40];   // padded LD=40 (reg-staged, fp32 convert)
  __shared__ bf16_t Bs[128 * 32];   // linear, global_load_lds + XOR swizzle

  const int n0g = blockIdx.x << 7;        // 0..2944 (global over 3072)
  const int z = n0g >> 10;                // which projection
  const float* A = z == 0 ? Qi : (z == 1 ? Ki : Vi);

  const int m0 = blockIdx.y << 7;
  const int tid = threadIdx.x;
  const int lane = tid & 63;
  const int w = tid >> 6;
  const int l15 = lane & 15;
  const int quad = lane >> 4;
  const int wy = (w >> 1) << 6;
  const int wx = (w & 1) << 6;
  const int w64 = w << 6;

  floatx4 acc[4][4];
#pragma unroll
  for (int i = 0; i < 4; i++)
#pragma unroll
    for (int j = 0; j < 4; j++)
#pragma unroll
      for (int r = 0; r < 4; r++) acc[i][j][r] = 0.0f;

  for (int kt = 0; kt < 32; kt++) {
    const int k0 = kt << 5;
    __syncthreads();
#pragma unroll
    for (int p = 0; p < 2; p++) {
      int slot = p * 256 + w64 + lane;
      int row = slot >> 2;
      int kc = (slot & 3) ^ (row & 3);
      load_lds16(&Wcat[(size_t)(n0g + row) * D_MODEL + k0 + (kc << 3)],
                 &Bs[(size_t)(p * 256 + w64) << 3]);
    }
#pragma unroll
    for (int p = 0; p < 4; p++) {
      int idx = p * 256 + tid;
      int r = idx >> 3, c = idx & 7;
      floatx4 v = *(const floatx4*)&A[(size_t)(m0 + r) * D_MODEL + k0 + (c << 2)];
      bf16x4 o;
      o[0] = (bf16_t)v[0]; o[1] = (bf16_t)v[1];
      o[2] = (bf16_t)v[2]; o[3] = (bf16_t)v[3];
      *(bf16x4*)&As[r * 40 + (c << 2)] = o;
    }
    __syncthreads();

    bf16x8 af[4], bfv[4];
#pragma unroll
    for (int mi = 0; mi < 4; mi++) {
      int m = wy + mi * 16 + l15;
      af[mi] = *(const bf16x8*)&As[m * 40 + (quad << 3)];
    }
#pragma unroll
    for (int ni = 0; ni < 4; ni++) {
      int n = wx + ni * 16 + l15;
      bfv[ni] = *(const bf16x8*)&Bs[n * 32 + ((quad ^ (n & 3)) << 3)];
    }
#pragma unroll
    for (int mi = 0; mi < 4; mi++)
#pragma unroll
      for (int ni = 0; ni < 4; ni++)
        acc[mi][ni] = __builtin_amdgcn_mfma_f32_16x16x32_bf16(
            af[mi], bfv[ni], acc[mi][ni], 0, 0, 0);
  }

  const float* bias = z == 0 ? bq : (z == 1 ? bk : bv);
  bf16_t* outp      = z == 0 ? qo : (z == 1 ? ko : vo);
  const float scl   = (z == 0) ? QSCALE : 1.0f;
#pragma unroll
  for (int mi = 0; mi < 4; mi++) {
#pragma unroll
    for (int ni = 0; ni < 4; ni++) {
      const int nn = (n0g + wx + ni * 16 + l15) & (D_MODEL - 1);
      const float bvv = bias[nn];
      const int h = nn >> 6, d = nn & 63;
#pragma unroll
      for (int r = 0; r < 4; r++) {
        const int m = m0 + wy + mi * 16 + quad * 4 + r;
        const int b = m >> 11, s = m & (S_LEN - 1);
        float v = (acc[mi][ni][r] + bvv) * scl;
        if (z < 2) {
          outp[((((size_t)(b * NHEAD + h) << 11) + s) << 6) + d] = (bf16_t)v;
        } else {
          outp[((((size_t)(b * NHEAD + h) << 6) + d) << 11) + s] = (bf16_t)v;
        }
      }
    }
  }
}

// ---------------------------------------------------------------------------
// Output GEMM: out = obuf(bf16) @ Wo + bo, fp32 out.
// ---------------------------------------------------------------------------
__global__ __launch_bounds__(256)
void out_gemm_kernel(const bf16_t* __restrict__ A, const bf16_t* __restrict__ Wt,
                     const float* __restrict__ bias, float* __restrict__ out)
{
  __shared__ bf16_t As[128 * 32];
  __shared__ bf16_t Bs[128 * 32];
  const int m0 = blockIdx.y << 7;
  const int n0 = blockIdx.x << 7;
  const int tid = threadIdx.x;
  const int lane = tid & 63;
  const int w = tid >> 6;
  const int l15 = lane & 15;
  const int quad = lane >> 4;
  const int wy = (w >> 1) << 6;
  const int wx = (w & 1) << 6;
  const int w64 = w << 6;

  floatx4 acc[4][4];
#pragma unroll
  for (int i = 0; i < 4; i++)
#pragma unroll
    for (int j = 0; j < 4; j++)
#pragma unroll
      for (int r = 0; r < 4; r++) acc[i][j][r] = 0.0f;

  for (int kt = 0; kt < 32; kt++) {
    const int k0 = kt << 5;
    __syncthreads();
#pragma unroll
    for (int p = 0; p < 2; p++) {
      int slot = p * 256 + w64 + lane;
      int row = slot >> 2;
      int kc = (slot & 3) ^ (row & 3);
      load_lds16(&A[(size_t)(m0 + row) * D_MODEL + k0 + (kc << 3)],
                 &As[(size_t)(p * 256 + w64) << 3]);
      load_lds16(&Wt[(size_t)(n0 + row) * D_MODEL + k0 + (kc << 3)],
                 &Bs[(size_t)(p * 256 + w64) << 3]);
    }
    __syncthreads();

    bf16x8 af[4], bfv[4];
#pragma unroll
    for (int mi = 0; mi < 4; mi++) {
      int m = wy + mi * 16 + l15;
      af[mi] = *(const bf16x8*)&As[m * 32 + ((quad ^ (m & 3)) << 3)];
    }
#pragma unroll
    for (int ni = 0; ni < 4; ni++) {
      int n = wx + ni * 16 + l15;
      bfv[ni] = *(const bf16x8*)&Bs[n * 32 + ((quad ^ (n & 3)) << 3)];
    }
#pragma unroll
    for (int mi = 0; mi < 4; mi++)
#pragma unroll
      for (int ni = 0; ni < 4; ni++)
        acc[mi][ni] = __builtin_amdgcn_mfma_f32_16x16x32_bf16(
            af[mi], bfv[ni], acc[mi][ni], 0, 0, 0);
  }

#pragma unroll
  for (int mi = 0; mi < 4; mi++) {
#pragma unroll
    for (int ni = 0; ni < 4; ni++) {
      const int nbase = n0 + wx + ni * 16 + l15;
      const float bv = bias[nbase];
#pragma unroll
      for (int r = 0; r < 4; r++) {
        const int m = m0 + wy + mi * 16 + quad * 4 + r;
        out[((size_t)m << 10) + nbase] = acc[mi][ni][r] + bv;
      }
    }
  }
}

// ---------------------------------------------------------------------------
// Causal flash attention, S^T formulation, BALANCED pairing.
// 64-row q-tiles (32 total). Block x = pair p handles q-tile (31-p) then (p):
// every block runs exactly 33 k-tile bodies -> uniform duration, occupancy
// stays ~4 blocks/CU for the whole kernel. 4 waves x 16 q-rows.
// Per-body math = r4-verified S^T + ds_bpermute register exchange (mi removed).
// K/V double-buffered in LDS via global_load_lds; cross-phase prefetch keeps
// the pipeline full at the tile-A -> tile-B seam.
// ---------------------------------------------------------------------------
__global__ __launch_bounds__(256, 4)
void attn_kernel(const bf16_t* __restrict__ qp, const bf16_t* __restrict__ kp,
                 const bf16_t* __restrict__ vtp, bf16_t* __restrict__ ob)
{
  __shared__ bf16_t Kt0[64 * 64];
  __shared__ bf16_t Kt1[64 * 64];
  __shared__ bf16_t Vt0[64 * 64];
  __shared__ bf16_t Vt1[64 * 64];

  const int pair = blockIdx.x;             // 0..15
  const int bh = blockIdx.y;               // 0..63
  const int tid = threadIdx.x;
  const int w = tid >> 6;
  const int lane = tid & 63;
  const int l15 = lane & 15;
  const int quad = lane >> 4;

  const bf16_t* Qh = qp + ((size_t)bh << 17);
  const bf16_t* Kh = kp + ((size_t)bh << 17);
  const bf16_t* Vh = vtp + ((size_t)bh << 17);   // [64][2048]
  const int b = bh >> 4, h = bh & 15;

  auto stage = [&](int k0s, bf16_t* dK, bf16_t* dV) {
#pragma unroll
    for (int p = 0; p < 2; p++) {
      const int sbase = (w << 7) + (p << 6);
      const int slot = sbase + lane;
      const int row = slot >> 3;
      const int c = (slot & 7) ^ (row & 7);
      load_lds16(&Kh[((size_t)(k0s + row) << 6) + (c << 3)], &dK[sbase << 3]);
      load_lds16(&Vh[((size_t)row << 11) + k0s + (c << 3)], &dV[sbase << 3]);
    }
  };

  int par = 0;   // global tile-counter parity: current buffer index

  // One q-tile phase: qt in 64-row units; k-tiles 0..qt (inclusive diagonal).
  auto phase = [&](int qt, bool prefetch_next_phase) {
    const int q0 = qt << 6;
    const int qbase = q0 + (w << 4);       // wave's 16 q-rows
    const int nkb = qt + 1;

    bf16x8 qf[2];
#pragma unroll
    for (int ks = 0; ks < 2; ks++)
      qf[ks] = *(const bf16x8*)&Qh[(size_t)(qbase + l15) * DK +
                                   ks * 32 + (quad << 3)];

    floatx4 acc_o[4];
    float m_i = -1e30f, l_i = 0.0f;
#pragma unroll
    for (int nd = 0; nd < 4; nd++)
#pragma unroll
      for (int r = 0; r < 4; r++) acc_o[nd][r] = 0.0f;

    for (int kb = 0; kb < nkb; kb++) {
      const int k0 = kb << 6;
      __syncthreads();   // drains this tile's gll (issued one body ago)

      const bf16_t* cK = par ? Kt1 : Kt0;
      const bf16_t* cV = par ? Vt1 : Vt0;
      bf16_t* nK = par ? Kt0 : Kt1;
      bf16_t* nV = par ? Vt0 : Vt1;

      // prefetch next tile (next phase's tile 0 at the seam)
      if (kb + 1 < nkb)            stage((kb + 1) << 6, nK, nV);
      else if (prefetch_next_phase) stage(0, nK, nV);

      // ---- K frags (A-operand of S^T): m=key=ni*16+l15, k=ks*32+quad*8 ----
      bf16x8 bk[2][4];
#pragma unroll
      for (int ks = 0; ks < 2; ks++)
#pragma unroll
        for (int ni = 0; ni < 4; ni++) {
          const int row = ni * 16 + l15;
          const int cp = ((ks << 2) + quad) ^ (row & 7);
          bk[ks][ni] = *(const bf16x8*)&cK[(row << 6) + (cp << 3)];
        }

      // ---- S^T = K Q^T: lane holds q=l15 row, key=k0+ni*16+quad*4+r ----
      floatx4 st[4];
#pragma unroll
      for (int ni = 0; ni < 4; ni++)
#pragma unroll
        for (int r = 0; r < 4; r++) st[ni][r] = 0.0f;
#pragma unroll
      for (int ks = 0; ks < 2; ks++)
#pragma unroll
        for (int ni = 0; ni < 4; ni++)
          st[ni] = __builtin_amdgcn_mfma_f32_16x16x32_bf16(
              bk[ks][ni], qf[ks], st[ni], 0, 0, 0);

      // ---- causal mask (diagonal tile only) ----
      if (k0 + 63 > qbase) {
        const int qrow = qbase + l15;
#pragma unroll
        for (int ni = 0; ni < 4; ni++) {
          const int keyb = k0 + ni * 16 + quad * 4;
#pragma unroll
          for (int r = 0; r < 4; r++)
            if (keyb + r > qrow) st[ni][r] = -1e30f;
        }
      }

      // ---- row stats: in-register + 2 shuffles ----
      float v = st[0][0];
#pragma unroll
      for (int ni = 0; ni < 4; ni++)
#pragma unroll
        for (int r = 0; r < 4; r++) v = fmaxf(v, st[ni][r]);
      v = fmaxf(v, __shfl_xor(v, 16));
      v = fmaxf(v, __shfl_xor(v, 32));
      const float mn = fmaxf(m_i, v);
      const float alpha = __builtin_amdgcn_exp2f(m_i - mn);
      m_i = mn;

      // ---- P = exp2(S - m), packed; row sum ----
      unsigned pd[4][2];
      float s = 0.0f;
#pragma unroll
      for (int c = 0; c < 4; c++)
#pragma unroll
        for (int hh = 0; hh < 2; hh++) {
          float p0 = __builtin_amdgcn_exp2f(st[c][2 * hh]     - m_i);
          float p1 = __builtin_amdgcn_exp2f(st[c][2 * hh + 1] - m_i);
          s += p0 + p1;
          pd[c][hh] = pack_bf16(p0, p1);
        }
      s += __shfl_xor(s, 16);
      s += __shfl_xor(s, 32);
      l_i = l_i * alpha + s;

      // ---- broadcast alpha to O C-layout rows & rescale ----
#pragma unroll
      for (int r = 0; r < 4; r++) {
        float ab = bperm_f((quad * 4 + r) << 2, alpha);
#pragma unroll
        for (int nd = 0; nd < 4; nd++) acc_o[nd][r] *= ab;
      }

      // ---- register exchange: P (C-layout) -> PV A-operand layout ----
      union AV { unsigned u[4]; bf16x8 v; };
      AV av[2];
#pragma unroll
      for (int ks = 0; ks < 2; ks++)
#pragma unroll
        for (int i = 0; i < 4; i++) {
          const int addr = ((((2 * quad + (i >> 1)) & 3) << 4) | l15) << 2;
          int lo = __builtin_amdgcn_ds_bpermute(addr, (int)pd[ks * 2][i & 1]);
          int hi = __builtin_amdgcn_ds_bpermute(addr, (int)pd[ks * 2 + 1][i & 1]);
          av[ks].u[i] = (unsigned)(quad >= 2 ? hi : lo);
        }

      // ---- O += P V (V^T frags from LDS) ----
#pragma unroll
      for (int ks = 0; ks < 2; ks++) {
        bf16x8 bvv[4];
#pragma unroll
        for (int nd = 0; nd < 4; nd++) {
          const int row = nd * 16 + l15;
          const int cp = ((ks << 2) + quad) ^ (row & 7);
          bvv[nd] = *(const bf16x8*)&cV[(row << 6) + (cp << 3)];
        }
#pragma unroll
        for (int nd = 0; nd < 4; nd++)
          acc_o[nd] = __builtin_amdgcn_mfma_f32_16x16x32_bf16(
              av[ks].v, bvv[nd], acc_o[nd], 0, 0, 0);
      }

      par ^= 1;
    }

    // ---- phase epilogue: O /= l, write [B, S, H*64] bf16 ----
    const float inv = 1.0f / l_i;
#pragma unroll
    for (int r = 0; r < 4; r++) {
      const float linv = bperm_f((quad * 4 + r) << 2, inv);
      const int sRow = qbase + quad * 4 + r;
#pragma unroll
      for (int nd = 0; nd < 4; nd++) {
        const int d = nd * 16 + l15;
        ob[(((size_t)(b * S_LEN + sRow)) << 10) + h * 64 + d] =
            (bf16_t)(acc_o[nd][r] * linv);
      }
    }
  };

  stage(0, Kt0, Vt0);            // tile 0 of phase A into buffer 0
  phase(31 - pair, true);        // big tile first; prefetch B's tile 0 at seam
  phase(pair, false);            // total bodies = (32-p) + (p+1) = 33, uniform
}

// ---------------------------------------------------------------------------
extern "C" void kernel_launch(void* const* d_in, const int* in_sizes, int n_in,
                              void* d_out, int out_size, void* d_ws, size_t ws_size,
                              hipStream_t stream)
{
  (void)in_sizes; (void)n_in; (void)out_size; (void)ws_size;
  const float* Q  = (const float*)d_in[0];
  const float* K  = (const float*)d_in[1];
  const float* V  = (const float*)d_in[2];
  const float* Wq = (const float*)d_in[4];
  const float* bq = (const float*)d_in[5];
  const float* Wk = (const float*)d_in[6];
  const float* bk = (const float*)d_in[7];
  const float* Wv = (const float*)d_in[8];
  const float* bv = (const float*)d_in[9];
  const float* Wo = (const float*)d_in[10];
  const float* bo = (const float*)d_in[11];
  float* out = (float*)d_out;

  const size_t NELT = (size_t)MROWS * D_MODEL;
  bf16_t* qp   = (bf16_t*)d_ws;                     // [B,H,S,DK] (pre-scaled)
  bf16_t* kp   = qp + NELT;                         // [B,H,S,DK]
  bf16_t* vtp  = kp + NELT;                         // [B,H,DK,S]
  bf16_t* obuf = vtp + NELT;                        // [B,S,H*DK]
  bf16_t* wqt  = obuf + NELT;                       // [3072][1024] contiguous:
  bf16_t* wkt  = wqt + (size_t)D_MODEL * D_MODEL;   //   wqt | wkt | wvt
  bf16_t* wvt  = wkt + (size_t)D_MODEL * D_MODEL;
  bf16_t* wot  = wvt + (size_t)D_MODEL * D_MODEL;

  dim3 blk(256);
  transpose_w_kernel<<<dim3(16, 16, 4), blk, 0, stream>>>(
      Wq, Wk, Wv, Wo, wqt, wkt, wvt, wot);

  qkv_kernel<<<dim3(3 * D_MODEL / 128, MROWS / 128), blk, 0, stream>>>(
      Q, K, V, wqt, bq, bk, bv, qp, kp, vtp);

  attn_kernel<<<dim3(16, BATCH * NHEAD), blk, 0, stream>>>(qp, kp, vtp, obuf);

  out_gemm_kernel<<<dim3(D_MODEL / 128, MROWS / 128), blk, 0, stream>>>(
      obuf, wot, bo, out);
}

// Round 6
// 372.080 us; speedup vs baseline: 1.7103x; 1.0424x over previous
//
#include <hip/hip_runtime.h>

typedef __bf16 bf16_t;
typedef __bf16 bf16x8 __attribute__((ext_vector_type(8)));
typedef __bf16 bf16x4 __attribute__((ext_vector_type(4)));
typedef float  floatx4 __attribute__((ext_vector_type(4)));

#define D_MODEL 1024
#define S_LEN   2048
#define NHEAD   16
#define DK      64
#define BATCH   4
#define MROWS   (BATCH * S_LEN)   // 8192
// 1/sqrt(64) * log2(e): fold into Q so scores arrive in exp2 domain
#define QSCALE  0.18033688011112042f

__device__ __forceinline__ void load_lds16(const void* gsrc, void* ldst) {
  __builtin_amdgcn_global_load_lds(
      (const __attribute__((address_space(1))) void*)gsrc,
      (__attribute__((address_space(3))) void*)ldst, 16, 0, 0);
}

__device__ __forceinline__ unsigned pack_bf16(float a, float b) {
  union { bf16_t h[2]; unsigned u; } t;
  t.h[0] = (bf16_t)a; t.h[1] = (bf16_t)b;
  return t.u;
}

__device__ __forceinline__ float bperm_f(int addr, float v) {
  union { float f; int i; } in, out;
  in.f = v;
  out.i = __builtin_amdgcn_ds_bpermute(addr, in.i);
  return out.f;
}

// ---------------------------------------------------------------------------
// Fused weight transpose + fp32->bf16 for all 4 weights (z selects).
// wqt/wkt/wvt are contiguous -> form a [3072][1024] matrix for the QKV GEMM.
// ---------------------------------------------------------------------------
__global__ __launch_bounds__(256)
void transpose_w_kernel(const float* __restrict__ W0, const float* __restrict__ W1,
                        const float* __restrict__ W2, const float* __restrict__ W3,
                        bf16_t* __restrict__ T0, bf16_t* __restrict__ T1,
                        bf16_t* __restrict__ T2, bf16_t* __restrict__ T3)
{
  const int z = blockIdx.z;
  const float* W = z == 0 ? W0 : (z == 1 ? W1 : (z == 2 ? W2 : W3));
  bf16_t* Wt     = z == 0 ? T0 : (z == 1 ? T1 : (z == 2 ? T2 : T3));

  __shared__ float tile[64][65];
  const int x0 = blockIdx.x * 64;         // n
  const int y0 = blockIdx.y * 64;         // k
  const int tid = threadIdx.x;
  const int r = tid >> 4;
  const int c = (tid & 15) << 2;
#pragma unroll
  for (int p = 0; p < 4; p++) {
    floatx4 v = *(const floatx4*)&W[(size_t)(y0 + p * 16 + r) * D_MODEL + x0 + c];
    tile[p * 16 + r][c + 0] = v[0];
    tile[p * 16 + r][c + 1] = v[1];
    tile[p * 16 + r][c + 2] = v[2];
    tile[p * 16 + r][c + 3] = v[3];
  }
  __syncthreads();
#pragma unroll
  for (int p = 0; p < 4; p++) {
    int row = p * 16 + r;
    bf16x4 o;
    o[0] = (bf16_t)tile[c + 0][row];
    o[1] = (bf16_t)tile[c + 1][row];
    o[2] = (bf16_t)tile[c + 2][row];
    o[3] = (bf16_t)tile[c + 3][row];
    *(bf16x4*)&Wt[(size_t)(x0 + row) * D_MODEL + y0 + c] = o;
  }
}

// ---------------------------------------------------------------------------
// Fused QKV projection, fully-async staging:
//   A (fp32) -> LDS raw via global_load_lds (16B chunks, XOR swizzle),
//     converted fp32->bf16 at fragment-read time.
//   W (bf16, Wcat [3072][1024]) -> LDS via global_load_lds (XOR swizzle).
// XCD-locality swizzle: the 8 blocks sharing one (z,y) A-stripe get linear
// ids L = (s>>3)*64 + j*8 + (s&7)  (s = z*64+y, j = x&7) -> L % 8 == s % 8,
// so one stripe lands on ONE XCD's L2 (dispatch round-robin assumption,
// perf-only). grid (24, 64).
// ---------------------------------------------------------------------------
__global__ __launch_bounds__(256, 3)
void qkv_kernel(const float* __restrict__ Qi, const float* __restrict__ Ki,
                const float* __restrict__ Vi, const bf16_t* __restrict__ Wcat,
                const float* __restrict__ bq, const float* __restrict__ bk,
                const float* __restrict__ bv,
                bf16_t* __restrict__ qo, bf16_t* __restrict__ ko,
                bf16_t* __restrict__ vo)
{
  __shared__ float  Asf[128 * 32];  // fp32 A tile, 16B-chunk XOR swizzle
  __shared__ bf16_t Bs[128 * 32];   // bf16 W tile, XOR swizzle

  // ---- XCD-locality decode ----
  const int L = blockIdx.x + 24 * blockIdx.y;     // 0..1535
  const int j = (L >> 3) & 7;
  const int s = ((L >> 6) << 3) | (L & 7);        // stripe 0..191
  const int z = s >> 6;                           // projection
  const int n0g = (((z << 3) | j)) << 7;          // global n over 3072
  const int m0 = (s & 63) << 7;

  const float* A = z == 0 ? Qi : (z == 1 ? Ki : Vi);

  const int tid = threadIdx.x;
  const int lane = tid & 63;
  const int w = tid >> 6;
  const int l15 = lane & 15;
  const int quad = lane >> 4;
  const int wy = (w >> 1) << 6;
  const int wx = (w & 1) << 6;
  const int w64 = w << 6;

  floatx4 acc[4][4];
#pragma unroll
  for (int i = 0; i < 4; i++)
#pragma unroll
    for (int jj = 0; jj < 4; jj++)
#pragma unroll
      for (int r = 0; r < 4; r++) acc[i][jj][r] = 0.0f;

  for (int kt = 0; kt < 32; kt++) {
    const int k0 = kt << 5;
    __syncthreads();
    // W: 512 chunks of 8 bf16; slot -> (row=slot>>2, kc=(slot&3)^(row&3))
#pragma unroll
    for (int p = 0; p < 2; p++) {
      int slot = p * 256 + w64 + lane;
      int row = slot >> 2;
      int kc = (slot & 3) ^ (row & 3);
      load_lds16(&Wcat[(size_t)(n0g + row) * D_MODEL + k0 + (kc << 3)],
                 &Bs[(size_t)(p * 256 + w64) << 3]);
    }
    // A: 1024 chunks of 4 fp32; slot -> (row=slot>>3, ca=(slot&7)^(row&7))
#pragma unroll
    for (int p = 0; p < 4; p++) {
      int sbase = (w << 8) + (p << 6);
      int slot = sbase + lane;
      int row = slot >> 3;
      int ca = (slot & 7) ^ (row & 7);
      load_lds16(&A[(size_t)(m0 + row) * D_MODEL + k0 + (ca << 2)],
                 &Asf[(size_t)sbase << 2]);
    }
    __syncthreads();

    bf16x8 af[4], bfv[4];
#pragma unroll
    for (int mi = 0; mi < 4; mi++) {
      const int m = wy + mi * 16 + l15;
      const int e = m & 7;
      floatx4 f0 = *(const floatx4*)&Asf[(m << 5) + ((((quad << 1))     ^ e) << 2)];
      floatx4 f1 = *(const floatx4*)&Asf[(m << 5) + ((((quad << 1) | 1) ^ e) << 2)];
      bf16x8 o;
      o[0] = (bf16_t)f0[0]; o[1] = (bf16_t)f0[1];
      o[2] = (bf16_t)f0[2]; o[3] = (bf16_t)f0[3];
      o[4] = (bf16_t)f1[0]; o[5] = (bf16_t)f1[1];
      o[6] = (bf16_t)f1[2]; o[7] = (bf16_t)f1[3];
      af[mi] = o;
    }
#pragma unroll
    for (int ni = 0; ni < 4; ni++) {
      int n = wx + ni * 16 + l15;
      bfv[ni] = *(const bf16x8*)&Bs[n * 32 + ((quad ^ (n & 3)) << 3)];
    }
#pragma unroll
    for (int mi = 0; mi < 4; mi++)
#pragma unroll
      for (int ni = 0; ni < 4; ni++)
        acc[mi][ni] = __builtin_amdgcn_mfma_f32_16x16x32_bf16(
            af[mi], bfv[ni], acc[mi][ni], 0, 0, 0);
  }

  const float* bias = z == 0 ? bq : (z == 1 ? bk : bv);
  bf16_t* outp      = z == 0 ? qo : (z == 1 ? ko : vo);
  const float scl   = (z == 0) ? QSCALE : 1.0f;
#pragma unroll
  for (int mi = 0; mi < 4; mi++) {
#pragma unroll
    for (int ni = 0; ni < 4; ni++) {
      const int nn = (n0g + wx + ni * 16 + l15) & (D_MODEL - 1);
      const float bvv = bias[nn];
      const int h = nn >> 6, d = nn & 63;
#pragma unroll
      for (int r = 0; r < 4; r++) {
        const int m = m0 + wy + mi * 16 + quad * 4 + r;
        const int b = m >> 11, srow = m & (S_LEN - 1);
        float v = (acc[mi][ni][r] + bvv) * scl;
        if (z < 2) {
          outp[((((size_t)(b * NHEAD + h) << 11) + srow) << 6) + d] = (bf16_t)v;
        } else {
          outp[((((size_t)(b * NHEAD + h) << 6) + d) << 11) + srow] = (bf16_t)v;
        }
      }
    }
  }
}

// ---------------------------------------------------------------------------
// Output GEMM: out = obuf(bf16) @ Wo + bo, fp32 out. Dual global_load_lds.
// Same XCD-locality swizzle (8 x-blocks per A-stripe; 64 stripes).
// ---------------------------------------------------------------------------
__global__ __launch_bounds__(256)
void out_gemm_kernel(const bf16_t* __restrict__ A, const bf16_t* __restrict__ Wt,
                     const float* __restrict__ bias, float* __restrict__ out)
{
  __shared__ bf16_t As[128 * 32];
  __shared__ bf16_t Bs[128 * 32];
  const int L = blockIdx.x + 8 * blockIdx.y;      // 0..511
  const int n0 = (((L >> 3) & 7)) << 7;
  const int m0 = ((((L >> 6) << 3) | (L & 7))) << 7;
  const int tid = threadIdx.x;
  const int lane = tid & 63;
  const int w = tid >> 6;
  const int l15 = lane & 15;
  const int quad = lane >> 4;
  const int wy = (w >> 1) << 6;
  const int wx = (w & 1) << 6;
  const int w64 = w << 6;

  floatx4 acc[4][4];
#pragma unroll
  for (int i = 0; i < 4; i++)
#pragma unroll
    for (int jj = 0; jj < 4; jj++)
#pragma unroll
      for (int r = 0; r < 4; r++) acc[i][jj][r] = 0.0f;

  for (int kt = 0; kt < 32; kt++) {
    const int k0 = kt << 5;
    __syncthreads();
#pragma unroll
    for (int p = 0; p < 2; p++) {
      int slot = p * 256 + w64 + lane;
      int row = slot >> 2;
      int kc = (slot & 3) ^ (row & 3);
      load_lds16(&A[(size_t)(m0 + row) * D_MODEL + k0 + (kc << 3)],
                 &As[(size_t)(p * 256 + w64) << 3]);
      load_lds16(&Wt[(size_t)(n0 + row) * D_MODEL + k0 + (kc << 3)],
                 &Bs[(size_t)(p * 256 + w64) << 3]);
    }
    __syncthreads();

    bf16x8 af[4], bfv[4];
#pragma unroll
    for (int mi = 0; mi < 4; mi++) {
      int m = wy + mi * 16 + l15;
      af[mi] = *(const bf16x8*)&As[m * 32 + ((quad ^ (m & 3)) << 3)];
    }
#pragma unroll
    for (int ni = 0; ni < 4; ni++) {
      int n = wx + ni * 16 + l15;
      bfv[ni] = *(const bf16x8*)&Bs[n * 32 + ((quad ^ (n & 3)) << 3)];
    }
#pragma unroll
    for (int mi = 0; mi < 4; mi++)
#pragma unroll
      for (int ni = 0; ni < 4; ni++)
        acc[mi][ni] = __builtin_amdgcn_mfma_f32_16x16x32_bf16(
            af[mi], bfv[ni], acc[mi][ni], 0, 0, 0);
  }

#pragma unroll
  for (int mi = 0; mi < 4; mi++) {
#pragma unroll
    for (int ni = 0; ni < 4; ni++) {
      const int nbase = n0 + wx + ni * 16 + l15;
      const float bv = bias[nbase];
#pragma unroll
      for (int r = 0; r < 4; r++) {
        const int m = m0 + wy + mi * 16 + quad * 4 + r;
        out[((size_t)m << 10) + nbase] = acc[mi][ni][r] + bv;
      }
    }
  }
}

// ---------------------------------------------------------------------------
// Causal flash attention, S^T formulation, BALANCED pairing (r5-verified).
// ---------------------------------------------------------------------------
__global__ __launch_bounds__(256, 4)
void attn_kernel(const bf16_t* __restrict__ qp, const bf16_t* __restrict__ kp,
                 const bf16_t* __restrict__ vtp, bf16_t* __restrict__ ob)
{
  __shared__ bf16_t Kt0[64 * 64];
  __shared__ bf16_t Kt1[64 * 64];
  __shared__ bf16_t Vt0[64 * 64];
  __shared__ bf16_t Vt1[64 * 64];

  const int pair = blockIdx.x;             // 0..15
  const int bh = blockIdx.y;               // 0..63
  const int tid = threadIdx.x;
  const int w = tid >> 6;
  const int lane = tid & 63;
  const int l15 = lane & 15;
  const int quad = lane >> 4;

  const bf16_t* Qh = qp + ((size_t)bh << 17);
  const bf16_t* Kh = kp + ((size_t)bh << 17);
  const bf16_t* Vh = vtp + ((size_t)bh << 17);   // [64][2048]
  const int b = bh >> 4, h = bh & 15;

  auto stage = [&](int k0s, bf16_t* dK, bf16_t* dV) {
#pragma unroll
    for (int p = 0; p < 2; p++) {
      const int sbase = (w << 7) + (p << 6);
      const int slot = sbase + lane;
      const int row = slot >> 3;
      const int c = (slot & 7) ^ (row & 7);
      load_lds16(&Kh[((size_t)(k0s + row) << 6) + (c << 3)], &dK[sbase << 3]);
      load_lds16(&Vh[((size_t)row << 11) + k0s + (c << 3)], &dV[sbase << 3]);
    }
  };

  int par = 0;   // global tile-counter parity: current buffer index

  auto phase = [&](int qt, bool prefetch_next_phase) {
    const int q0 = qt << 6;
    const int qbase = q0 + (w << 4);       // wave's 16 q-rows
    const int nkb = qt + 1;

    bf16x8 qf[2];
#pragma unroll
    for (int ks = 0; ks < 2; ks++)
      qf[ks] = *(const bf16x8*)&Qh[(size_t)(qbase + l15) * DK +
                                   ks * 32 + (quad << 3)];

    floatx4 acc_o[4];
    float m_i = -1e30f, l_i = 0.0f;
#pragma unroll
    for (int nd = 0; nd < 4; nd++)
#pragma unroll
      for (int r = 0; r < 4; r++) acc_o[nd][r] = 0.0f;

    for (int kb = 0; kb < nkb; kb++) {
      const int k0 = kb << 6;
      __syncthreads();   // drains this tile's gll (issued one body ago)

      const bf16_t* cK = par ? Kt1 : Kt0;
      const bf16_t* cV = par ? Vt1 : Vt0;
      bf16_t* nK = par ? Kt0 : Kt1;
      bf16_t* nV = par ? Vt0 : Vt1;

      if (kb + 1 < nkb)             stage((kb + 1) << 6, nK, nV);
      else if (prefetch_next_phase) stage(0, nK, nV);

      bf16x8 bk[2][4];
#pragma unroll
      for (int ks = 0; ks < 2; ks++)
#pragma unroll
        for (int ni = 0; ni < 4; ni++) {
          const int row = ni * 16 + l15;
          const int cp = ((ks << 2) + quad) ^ (row & 7);
          bk[ks][ni] = *(const bf16x8*)&cK[(row << 6) + (cp << 3)];
        }

      floatx4 st[4];
#pragma unroll
      for (int ni = 0; ni < 4; ni++)
#pragma unroll
        for (int r = 0; r < 4; r++) st[ni][r] = 0.0f;
#pragma unroll
      for (int ks = 0; ks < 2; ks++)
#pragma unroll
        for (int ni = 0; ni < 4; ni++)
          st[ni] = __builtin_amdgcn_mfma_f32_16x16x32_bf16(
              bk[ks][ni], qf[ks], st[ni], 0, 0, 0);

      if (k0 + 63 > qbase) {
        const int qrow = qbase + l15;
#pragma unroll
        for (int ni = 0; ni < 4; ni++) {
          const int keyb = k0 + ni * 16 + quad * 4;
#pragma unroll
          for (int r = 0; r < 4; r++)
            if (keyb + r > qrow) st[ni][r] = -1e30f;
        }
      }

      float v = st[0][0];
#pragma unroll
      for (int ni = 0; ni < 4; ni++)
#pragma unroll
        for (int r = 0; r < 4; r++) v = fmaxf(v, st[ni][r]);
      v = fmaxf(v, __shfl_xor(v, 16));
      v = fmaxf(v, __shfl_xor(v, 32));
      const float mn = fmaxf(m_i, v);
      const float alpha = __builtin_amdgcn_exp2f(m_i - mn);
      m_i = mn;

      unsigned pd[4][2];
      float ssum = 0.0f;
#pragma unroll
      for (int c = 0; c < 4; c++)
#pragma unroll
        for (int hh = 0; hh < 2; hh++) {
          float p0 = __builtin_amdgcn_exp2f(st[c][2 * hh]     - m_i);
          float p1 = __builtin_amdgcn_exp2f(st[c][2 * hh + 1] - m_i);
          ssum += p0 + p1;
          pd[c][hh] = pack_bf16(p0, p1);
        }
      ssum += __shfl_xor(ssum, 16);
      ssum += __shfl_xor(ssum, 32);
      l_i = l_i * alpha + ssum;

#pragma unroll
      for (int r = 0; r < 4; r++) {
        float ab = bperm_f((quad * 4 + r) << 2, alpha);
#pragma unroll
        for (int nd = 0; nd < 4; nd++) acc_o[nd][r] *= ab;
      }

      union AV { unsigned u[4]; bf16x8 v; };
      AV av[2];
#pragma unroll
      for (int ks = 0; ks < 2; ks++)
#pragma unroll
        for (int i = 0; i < 4; i++) {
          const int addr = ((((2 * quad + (i >> 1)) & 3) << 4) | l15) << 2;
          int lo = __builtin_amdgcn_ds_bpermute(addr, (int)pd[ks * 2][i & 1]);
          int hi = __builtin_amdgcn_ds_bpermute(addr, (int)pd[ks * 2 + 1][i & 1]);
          av[ks].u[i] = (unsigned)(quad >= 2 ? hi : lo);
        }

#pragma unroll
      for (int ks = 0; ks < 2; ks++) {
        bf16x8 bvv[4];
#pragma unroll
        for (int nd = 0; nd < 4; nd++) {
          const int row = nd * 16 + l15;
          const int cp = ((ks << 2) + quad) ^ (row & 7);
          bvv[nd] = *(const bf16x8*)&cV[(row << 6) + (cp << 3)];
        }
#pragma unroll
        for (int nd = 0; nd < 4; nd++)
          acc_o[nd] = __builtin_amdgcn_mfma_f32_16x16x32_bf16(
              av[ks].v, bvv[nd], acc_o[nd], 0, 0, 0);
      }

      par ^= 1;
    }

    const float inv = 1.0f / l_i;
#pragma unroll
    for (int r = 0; r < 4; r++) {
      const float linv = bperm_f((quad * 4 + r) << 2, inv);
      const int sRow = qbase + quad * 4 + r;
#pragma unroll
      for (int nd = 0; nd < 4; nd++) {
        const int d = nd * 16 + l15;
        ob[(((size_t)(b * S_LEN + sRow)) << 10) + h * 64 + d] =
            (bf16_t)(acc_o[nd][r] * linv);
      }
    }
  };

  stage(0, Kt0, Vt0);            // tile 0 of phase A into buffer 0
  phase(31 - pair, true);        // big tile first; prefetch B's tile 0 at seam
  phase(pair, false);            // total bodies = (32-p) + (p+1) = 33, uniform
}

// ---------------------------------------------------------------------------
extern "C" void kernel_launch(void* const* d_in, const int* in_sizes, int n_in,
                              void* d_out, int out_size, void* d_ws, size_t ws_size,
                              hipStream_t stream)
{
  (void)in_sizes; (void)n_in; (void)out_size; (void)ws_size;
  const float* Q  = (const float*)d_in[0];
  const float* K  = (const float*)d_in[1];
  const float* V  = (const float*)d_in[2];
  const float* Wq = (const float*)d_in[4];
  const float* bq = (const float*)d_in[5];
  const float* Wk = (const float*)d_in[6];
  const float* bk = (const float*)d_in[7];
  const float* Wv = (const float*)d_in[8];
  const float* bv = (const float*)d_in[9];
  const float* Wo = (const float*)d_in[10];
  const float* bo = (const float*)d_in[11];
  float* out = (float*)d_out;

  const size_t NELT = (size_t)MROWS * D_MODEL;
  bf16_t* qp   = (bf16_t*)d_ws;                     // [B,H,S,DK] (pre-scaled)
  bf16_t* kp   = qp + NELT;                         // [B,H,S,DK]
  bf16_t* vtp  = kp + NELT;                         // [B,H,DK,S]
  bf16_t* obuf = vtp + NELT;                        // [B,S,H*DK]
  bf16_t* wqt  = obuf + NELT;                       // [3072][1024] contiguous:
  bf16_t* wkt  = wqt + (size_t)D_MODEL * D_MODEL;   //   wqt | wkt | wvt
  bf16_t* wvt  = wkt + (size_t)D_MODEL * D_MODEL;
  bf16_t* wot  = wvt + (size_t)D_MODEL * D_MODEL;

  dim3 blk(256);
  transpose_w_kernel<<<dim3(16, 16, 4), blk, 0, stream>>>(
      Wq, Wk, Wv, Wo, wqt, wkt, wvt, wot);

  qkv_kernel<<<dim3(3 * D_MODEL / 128, MROWS / 128), blk, 0, stream>>>(
      Q, K, V, wqt, bq, bk, bv, qp, kp, vtp);

  attn_kernel<<<dim3(16, BATCH * NHEAD), blk, 0, stream>>>(qp, kp, vtp, obuf);

  out_gemm_kernel<<<dim3(D_MODEL / 128, MROWS / 128), blk, 0, stream>>>(
      obuf, wot, bo, out);
}